// Round 5
// baseline (12788.506 us; speedup 1.0000x reference)
//
#include <hip/hip_runtime.h>
#include <hip/hip_bf16.h>
#include <float.h>

// LiDAR BEV pipeline (fp32 I/O, per reference):
//   voxelize -> conv3d(1->32)+BN+ReLU -> conv3d(32->64)+BN+ReLU -> conv3d(64->64)+BN+ReLU -> max over D
// fp32 compute; big activations stored bf16 (fp8 in the smallest plan). BN folded
// into the consumer's input load; conv kernels write raw conv+bias and accumulate
// per-channel sum/sumsq for BN stats. ws_size-adaptive plans (R1/R2 crashed on ws
// overrun; ws_size is known to be in [~151MB, 341MB) -> Plan B expected):
//   Plan A (~341MB+margin): store x1,x2,x3 bf16; single conv3 pass; bev max kernel.
//   Plan B (~171MB): fused conv1+conv2 (recompute conv1 per tile), store only x2 bf16;
//                    conv3 twice (stats pass, then fused conv3+BN+ReLU+max over D-slab).
//   Plan C (~105MB): Plan B with x2 stored fp8 e4m3.

#define VOXEL 0.0625f
#define D_ 128
#define H_ 128
#define W_ 32
#define HW_ (H_*W_)      // 4096
#define DHW_ (D_*H_*W_)  // 524288
#define B_ 2
#define EPSV 1e-5f
#define OUTN_ (B_*64*HW_) // 524288

typedef __hip_bfloat16 bf16;

// ---- fp8 e4m3fn storage (hand-rolled; only used by Plan C) ----
struct fp8s { unsigned char v; };

__device__ inline float e4m3f(unsigned char c){
  int e = (c >> 3) & 0xF, m = c & 7;
  float x = e ? ldexpf((float)(8 + m), e - 10) : ldexpf((float)m, -9);
  return (c & 0x80) ? -x : x;
}
__device__ inline unsigned char f2e4m3(float x){
  unsigned u = __float_as_uint(x);
  unsigned s = (u >> 24) & 0x80u;
  float a = fabsf(x);
  if (a >= 448.f) return (unsigned char)(s | 0x7E);
  if (a < 0.015625f){                       // denormal range, quantum 2^-9
    int n = __float2int_rn(a * 512.f);      // 0..8 (8 == 2^-6, code 0x08)
    return (unsigned char)(s | (unsigned)n);
  }
  unsigned b = __float_as_uint(a);
  b += 0x7FFFFu + ((b >> 20) & 1u);         // RNE into 3-bit mantissa
  int e = (int)((b >> 23) & 0xFF) - 127;
  unsigned m = (b >> 20) & 7u;
  if (e > 8 || (e == 8 && m == 7)) return (unsigned char)(s | 0x7E);
  return (unsigned char)(s | ((unsigned)(e + 7) << 3) | m);
}

__device__ inline float ldf(const float* p){ return *p; }
__device__ inline float ldf(const bf16* p){ return __bfloat162float(*p); }
__device__ inline float ldf(const fp8s* p){ return e4m3f(p->v); }
__device__ inline void stf(float* p, float v){ *p = v; }
__device__ inline void stf(bf16* p, float v){ *p = __float2bfloat16(v); }
__device__ inline void stf(fp8s* p, float v){ p->v = f2e4m3(v); }

// ---------------- init ----------------

__global__ void zero_kernel(float* __restrict__ p, int n){
  int i = blockIdx.x*blockDim.x + threadIdx.x;
  if (i < n) p[i] = 0.f;
}

// ---------------- voxelize ----------------

__global__ void min_kernel(const float* __restrict__ pc, float* __restrict__ mins, int N){
  const float* base = pc + (size_t)blockIdx.x * N;
  float m = FLT_MAX;
  for (int j = threadIdx.x; j < N; j += blockDim.x){
    float v = base[j];
    if (v != v) v = 0.f;          // NaN -> 0, matching reference
    m = fminf(m, v);
  }
  for (int off = 32; off > 0; off >>= 1)
    m = fminf(m, __shfl_xor(m, off, 64));
  __shared__ float red[4];
  int wave = threadIdx.x >> 6;
  if ((threadIdx.x & 63) == 0) red[wave] = m;
  __syncthreads();
  if (threadIdx.x == 0){
    float r = red[0];
    for (int k = 1; k < (int)(blockDim.x >> 6); ++k) r = fminf(r, red[k]);
    mins[blockIdx.x] = r;
  }
}

__global__ void scatter_kernel(const float* __restrict__ pc, const float* __restrict__ mins,
                               float* __restrict__ grid, int N){
  int idx = blockIdx.x*blockDim.x + threadIdx.x;
  if (idx >= B_*N) return;
  int b = idx / N, n = idx - b*N;
  float x = pc[((size_t)b*3 + 0)*N + n];
  float y = pc[((size_t)b*3 + 1)*N + n];
  float z = pc[((size_t)b*3 + 2)*N + n];
  if (x != x) x = 0.f;
  if (y != y) y = 0.f;
  if (z != z) z = 0.f;
  int ix = (int)floorf((x - mins[b*3+0]) / VOXEL);
  int iy = (int)floorf((y - mins[b*3+1]) / VOXEL);
  int iz = (int)floorf((z - mins[b*3+2]) / VOXEL);
  ix = min(max(ix, 0), D_-1);
  iy = min(max(iy, 0), H_-1);
  iz = min(max(iz, 0), W_-1);
  grid[(size_t)b*DHW_ + (size_t)ix*HW_ + iy*W_ + iz] = 1.0f;
}

// ---------------- weight reorder: (O,I,3,3,3) -> (I,27,O) ----------------

__global__ void reorder_kernel(const float* __restrict__ w, float* __restrict__ wr, int CIN, int COUT){
  int idx = blockIdx.x*blockDim.x + threadIdx.x;
  int total = COUT*CIN*27;
  if (idx >= total) return;
  int o = idx / (CIN*27);
  int rem = idx - o*(CIN*27);
  int i = rem / 27;
  int k = rem - i*27;
  wr[(i*27 + k)*COUT + o] = w[idx];
}

// ---------------- shared conv inner: 27-tap accumulate from LDS tile ----------------
// 256 threads = 32 w-lanes x 8 o-groups; thread accumulates 8h x OPT o.

template<int OPT, int COUT>
__device__ inline void conv_inner(float (*xs)[10][34], float (*wsm)[COUT],
                                  int w, int og, float (*acc)[OPT]){
  #pragma unroll
  for (int kd = 0; kd < 3; ++kd){
    float xr[10][3];
    #pragma unroll
    for (int r = 0; r < 10; ++r)
      #pragma unroll
      for (int c = 0; c < 3; ++c)
        xr[r][c] = xs[kd][r][w + c];
    #pragma unroll
    for (int kh = 0; kh < 3; ++kh)
      #pragma unroll
      for (int kw = 0; kw < 3; ++kw){
        const float* wp = &wsm[kd*9 + kh*3 + kw][og*OPT];
        float wv[OPT];
        #pragma unroll
        for (int oo = 0; oo < OPT; ++oo) wv[oo] = wp[oo];
        #pragma unroll
        for (int h = 0; h < 8; ++h){
          float xv = xr[h + kh][kw];
          #pragma unroll
          for (int oo = 0; oo < OPT; ++oo)
            acc[h][oo] = fmaf(xv, wv[oo], acc[h][oo]);
        }
      }
  }
}

// ---------------- generic conv3d 3x3x3 SAME + bias (+optional BN on input, optional store) ----------------

template<int CIN, int COUT, bool BN_IN, bool STORE, typename TIn, typename TOut>
__global__ __launch_bounds__(256)
void conv_kernel(const TIn* __restrict__ X, const float* __restrict__ WR,
                 const float* __restrict__ bias, const float* __restrict__ ssIn,
                 TOut* __restrict__ Y, float* __restrict__ stats){
  static_assert(COUT % 8 == 0, "");
  constexpr int OPT = COUT / 8;
  const int tid = threadIdx.x;
  const int w   = tid & 31;
  const int og  = tid >> 5;
  const int h0  = blockIdx.x * 8;
  const int d   = blockIdx.y;
  const int b   = blockIdx.z;

  __shared__ float xs[3][10][34];
  __shared__ float wsm[27][COUT];

  float acc[8][OPT];
  #pragma unroll
  for (int h = 0; h < 8; ++h)
    #pragma unroll
    for (int oo = 0; oo < OPT; ++oo) acc[h][oo] = 0.f;

  for (int i = 0; i < CIN; ++i){
    __syncthreads();
    for (int e = tid; e < 27*COUT; e += 256)
      ((float*)wsm)[e] = WR[i*27*COUT + e];
    float a_ = 1.f, s_ = 0.f;
    if (BN_IN){ a_ = ssIn[i]; s_ = ssIn[CIN + i]; }
    for (int e = tid; e < 960; e += 256){
      int ds = e / 320; int rem = e - ds*320; int r = rem >> 5; int ww = rem & 31;
      int dd = d + ds - 1, hh = h0 + r - 1;
      float v = 0.f;
      if (dd >= 0 && dd < D_ && hh >= 0 && hh < H_){
        v = ldf(&X[((size_t)(b*CIN + i)*D_ + dd)*HW_ + hh*W_ + ww]);
        if (BN_IN) v = fmaxf(fmaf(a_, v, s_), 0.f);
      }
      xs[ds][r][ww + 1] = v;
    }
    if (tid < 30){ int ds = tid/10, r = tid - ds*10; xs[ds][r][0] = 0.f; xs[ds][r][33] = 0.f; }
    __syncthreads();
    conv_inner<OPT, COUT>(xs, wsm, w, og, acc);
  }

  // epilogue: bias, optional store, per-channel sum/sumsq
  #pragma unroll
  for (int oo = 0; oo < OPT; ++oo){
    int o = og*OPT + oo;
    float bo = bias[o];
    float s1 = 0.f, s2 = 0.f;
    #pragma unroll
    for (int h = 0; h < 8; ++h){
      float y = acc[h][oo] + bo;
      if (STORE) stf(&Y[((size_t)(b*COUT + o)*D_ + d)*HW_ + (h0 + h)*W_ + w], y);
      s1 += y;
      s2 = fmaf(y, y, s2);
    }
    for (int m = 16; m > 0; m >>= 1){
      s1 += __shfl_xor(s1, m, 32);
      s2 += __shfl_xor(s2, m, 32);
    }
    if (w == 0){
      atomicAdd(&stats[o], s1);
      atomicAdd(&stats[COUT + o], s2);
    }
  }
}

// ---------------- fused conv1(1->32)+BN1+ReLU + conv2(32->64): recomputes conv1 per tile ----------------

template<typename TOut>
__global__ __launch_bounds__(256)
void fused12_kernel(const float* __restrict__ G0, const float* __restrict__ WR1,
                    const float* __restrict__ B1, const float* __restrict__ SS1,
                    const float* __restrict__ WR2, const float* __restrict__ B2,
                    TOut* __restrict__ X2, float* __restrict__ stats){
  const int tid = threadIdx.x;
  const int w   = tid & 31;
  const int og  = tid >> 5;
  const int h0  = blockIdx.x * 8;
  const int d   = blockIdx.y;
  const int b   = blockIdx.z;

  __shared__ float gs[5][12][34];    // occupancy tile (+2 halo in d/h, +1 in w)
  __shared__ float w1s[32][27];
  __shared__ float xs[3][10][34];    // x1 channel tile, post BN1+ReLU
  __shared__ float wsm[27][64];

  for (int e = tid; e < 5*12*34; e += 256){
    int ds = e / 408; int rem = e - ds*408; int r = rem / 34; int c = rem - r*34;
    int dd = d - 2 + ds, hh = h0 - 2 + r, ww = c - 1;
    float v = 0.f;
    if (c >= 1 && c <= 32 && dd >= 0 && dd < D_ && hh >= 0 && hh < H_)
      v = G0[((size_t)b*D_ + dd)*HW_ + hh*W_ + ww];
    gs[ds][r][c] = v;
  }
  for (int e = tid; e < 864; e += 256){   // strided: 256 threads must cover 864 elems
    int i = e/27, k = e - 27*i;
    w1s[i][k] = WR1[k*32 + i];
  }

  float acc[8][8];
  #pragma unroll
  for (int h = 0; h < 8; ++h)
    #pragma unroll
    for (int oo = 0; oo < 8; ++oo) acc[h][oo] = 0.f;

  for (int i = 0; i < 32; ++i){
    __syncthreads();
    float a1 = SS1[i];
    float f1 = fmaf(a1, B1[i], SS1[32 + i]);   // a1*b1 + shift1
    // recompute x1 channel i over the 3x10x(32+halo) tile
    for (int e = tid; e < 1020; e += 256){
      int ds = e / 340; int rem = e - ds*340; int r = rem / 34; int c = rem - r*34;
      float v = 0.f;
      int dd = d - 1 + ds, hh = h0 - 1 + r;
      if (c >= 1 && c <= 32 && dd >= 0 && dd < D_ && hh >= 0 && hh < H_){
        float s = 0.f;
        #pragma unroll
        for (int kd = 0; kd < 3; ++kd)
          #pragma unroll
          for (int kh = 0; kh < 3; ++kh)
            #pragma unroll
            for (int kw = 0; kw < 3; ++kw)
              s = fmaf(gs[ds+kd][r+kh][c-1+kw], w1s[i][kd*9+kh*3+kw], s);
        v = fmaxf(fmaf(a1, s, f1), 0.f);
      }
      xs[ds][r][c] = v;
    }
    for (int e = tid; e < 27*64; e += 256)
      ((float*)wsm)[e] = WR2[i*27*64 + e];
    __syncthreads();
    conv_inner<8, 64>(xs, wsm, w, og, acc);
  }

  #pragma unroll
  for (int oo = 0; oo < 8; ++oo){
    int o = og*8 + oo;
    float bo = B2[o];
    float s1 = 0.f, s2 = 0.f;
    #pragma unroll
    for (int h = 0; h < 8; ++h){
      float y = acc[h][oo] + bo;
      stf(&X2[((size_t)(b*64 + o)*D_ + d)*HW_ + (h0 + h)*W_ + w], y);
      s1 += y;
      s2 = fmaf(y, y, s2);
    }
    for (int m = 16; m > 0; m >>= 1){
      s1 += __shfl_xor(s1, m, 32);
      s2 += __shfl_xor(s2, m, 32);
    }
    if (w == 0){
      atomicAdd(&stats[o], s1);
      atomicAdd(&stats[64 + o], s2);
    }
  }
}

// ---------------- fused conv3 + BN3 + ReLU + max over a D-slab ----------------

template<typename TIn, int DCHUNK>
__global__ __launch_bounds__(256)
void conv3max_kernel(const TIn* __restrict__ X, const float* __restrict__ WR,
                     const float* __restrict__ bias, const float* __restrict__ ssIn,
                     const float* __restrict__ ssOut, float* __restrict__ partials){
  const int tid = threadIdx.x;
  const int w   = tid & 31;
  const int og  = tid >> 5;
  const int h0  = blockIdx.x * 8;
  const int d0  = blockIdx.y * DCHUNK;
  const int b   = blockIdx.z;

  __shared__ float xs[3][10][34];
  __shared__ float wsm[27][64];

  float b3r[8], a3r[8], s3r[8];
  #pragma unroll
  for (int oo = 0; oo < 8; ++oo){
    int o = og*8 + oo;
    b3r[oo] = bias[o]; a3r[oo] = ssOut[o]; s3r[oo] = ssOut[64 + o];
  }
  float bevmax[8][8];
  #pragma unroll
  for (int h = 0; h < 8; ++h)
    #pragma unroll
    for (int oo = 0; oo < 8; ++oo) bevmax[h][oo] = 0.f;  // ReLU >= 0

  for (int d = d0; d < d0 + DCHUNK; ++d){
    float acc[8][8];
    #pragma unroll
    for (int h = 0; h < 8; ++h)
      #pragma unroll
      for (int oo = 0; oo < 8; ++oo) acc[h][oo] = 0.f;

    for (int i = 0; i < 64; ++i){
      __syncthreads();
      for (int e = tid; e < 27*64; e += 256)
        ((float*)wsm)[e] = WR[i*27*64 + e];
      float a_ = ssIn[i], s_ = ssIn[64 + i];
      for (int e = tid; e < 960; e += 256){
        int ds = e / 320; int rem = e - ds*320; int r = rem >> 5; int ww = rem & 31;
        int dd = d + ds - 1, hh = h0 + r - 1;
        float v = 0.f;
        if (dd >= 0 && dd < D_ && hh >= 0 && hh < H_){
          v = ldf(&X[((size_t)(b*64 + i)*D_ + dd)*HW_ + hh*W_ + ww]);
          v = fmaxf(fmaf(a_, v, s_), 0.f);
        }
        xs[ds][r][ww + 1] = v;
      }
      if (tid < 30){ int ds = tid/10, r = tid - ds*10; xs[ds][r][0] = 0.f; xs[ds][r][33] = 0.f; }
      __syncthreads();
      conv_inner<8, 64>(xs, wsm, w, og, acc);
    }
    #pragma unroll
    for (int oo = 0; oo < 8; ++oo)
      #pragma unroll
      for (int h = 0; h < 8; ++h){
        float v = fmaxf(fmaf(a3r[oo], acc[h][oo] + b3r[oo], s3r[oo]), 0.f);
        bevmax[h][oo] = fmaxf(bevmax[h][oo], v);
      }
  }

  const size_t slab = (size_t)blockIdx.y * OUTN_;
  #pragma unroll
  for (int oo = 0; oo < 8; ++oo){
    int o = og*8 + oo;
    #pragma unroll
    for (int h = 0; h < 8; ++h)
      partials[slab + ((size_t)(b*64 + o))*HW_ + (h0 + h)*W_ + w] = bevmax[h][oo];
  }
}

__global__ void maxreduce_kernel(const float* __restrict__ partials, float* __restrict__ out, int nslab){
  int j = blockIdx.x*blockDim.x + threadIdx.x;
  if (j >= OUTN_) return;
  float m = partials[j];
  for (int s = 1; s < nslab; ++s)
    m = fmaxf(m, partials[(size_t)s*OUTN_ + j]);
  out[j] = m;
}

// ---------------- BN finalize: scale = g*rsqrt(var+eps), shift = beta - mean*scale ----------------

__global__ void finalize_kernel(const float* __restrict__ stats, const float* __restrict__ gamma,
                                const float* __restrict__ beta, float* __restrict__ ss, int C){
  int c = threadIdx.x;
  if (c >= C) return;
  const float invCnt = 1.0f / (float)((size_t)B_*DHW_);
  float mean = stats[c] * invCnt;
  float var  = stats[C + c] * invCnt - mean*mean;
  float a = gamma[c] * rsqrtf(var + EPSV);
  ss[c]     = a;
  ss[C + c] = beta[c] - mean*a;
}

// ---------------- BN+ReLU + max over D (Plan A) ----------------

__global__ void bev_kernel(const bf16* __restrict__ x3, const float* __restrict__ ss,
                           float* __restrict__ out){
  int idx = blockIdx.x*blockDim.x + threadIdx.x;
  if (idx >= OUTN_) return;
  int w = idx & (W_-1);
  int h = (idx >> 5) & (H_-1);
  int o = (idx >> 12) & 63;
  int b = idx >> 18;
  float a = ss[o], sh = ss[64 + o];
  const bf16* p = x3 + (size_t)(b*64 + o)*DHW_ + h*W_ + w;
  float m = 0.f;
  for (int d = 0; d < D_; ++d){
    float v = fmaxf(fmaf(a, __bfloat162float(p[(size_t)d*HW_]), sh), 0.f);
    m = fmaxf(m, v);
  }
  out[idx] = m;
}

// ---------------- launch ----------------

extern "C" void kernel_launch(void* const* d_in, const int* in_sizes, int n_in,
                              void* d_out, int out_size, void* d_ws, size_t ws_size,
                              hipStream_t stream){
  const float* pc  = (const float*)d_in[0];
  const float* w1  = (const float*)d_in[1];
  const float* b1  = (const float*)d_in[2];
  const float* g1  = (const float*)d_in[3];
  const float* be1 = (const float*)d_in[4];
  const float* w2  = (const float*)d_in[5];
  const float* b2  = (const float*)d_in[6];
  const float* g2  = (const float*)d_in[7];
  const float* be2 = (const float*)d_in[8];
  const float* w3  = (const float*)d_in[9];
  const float* b3  = (const float*)d_in[10];
  const float* g3  = (const float*)d_in[11];
  const float* be3 = (const float*)d_in[12];
  const int N = in_sizes[0] / 6;  // (B=2, 3, N)
  float* out = (float*)d_out;

  char* wsb = (char*)d_ws;
  size_t off = 0;
  auto alloc = [&](size_t bytes)->char*{
    off = (off + 255) & ~(size_t)255;
    char* p = wsb + off; off += bytes; return p;
  };
  float* g0  = (float*)alloc((size_t)B_*DHW_*4);   // 4 MB
  float* wr1 = (float*)alloc(864*4);
  float* wr2 = (float*)alloc(55296*4);
  float* wr3 = (float*)alloc(110592*4);
  float* mins= (float*)alloc(8*4);
  float* st  = (float*)alloc(3*128*4);
  float* ss  = (float*)alloc(3*128*4);
  const size_t prefix = (off + 255) & ~(size_t)255;

  const size_t SX1   = (size_t)B_*32*DHW_*2;   // 64 MiB bf16
  const size_t SX2B  = (size_t)B_*64*DHW_*2;   // 128 MiB bf16
  const size_t SX2C  = (size_t)B_*64*DHW_;     // 64 MiB fp8
  const size_t SPART = (size_t)16*OUTN_*4;     // 32 MiB (16 D-slabs)
  const size_t needA = prefix + SX1 + SX2B + SX2B + 3*256 + ((size_t)32 << 20); // +32MB margin
  const size_t needB = prefix + SPART + SX2B + 2*256;

  // common prologue
  zero_kernel<<<(B_*DHW_ + 255)/256, 256, 0, stream>>>(g0, B_*DHW_);
  zero_kernel<<<2, 256, 0, stream>>>(st, 3*128);
  min_kernel<<<B_*3, 256, 0, stream>>>(pc, mins, N);
  scatter_kernel<<<(B_*N + 255)/256, 256, 0, stream>>>(pc, mins, g0, N);
  reorder_kernel<<<(864 + 255)/256, 256, 0, stream>>>(w1, wr1, 1, 32);
  reorder_kernel<<<(55296 + 255)/256, 256, 0, stream>>>(w2, wr2, 32, 64);
  reorder_kernel<<<(110592 + 255)/256, 256, 0, stream>>>(w3, wr3, 64, 64);

  dim3 cgrid(16, 128, 2);   // (h-tiles, d, b)

  if (ws_size >= needA){
    // ---- Plan A: store everything ----
    bf16* x1 = (bf16*)alloc(SX1);
    bf16* x2 = (bf16*)alloc(SX2B);
    bf16* x3 = (bf16*)alloc(SX2B);
    conv_kernel<1,32,false,true,float,bf16><<<cgrid, 256, 0, stream>>>(g0, wr1, b1, nullptr, x1, st);
    finalize_kernel<<<1, 64, 0, stream>>>(st, g1, be1, ss, 32);
    conv_kernel<32,64,true,true,bf16,bf16><<<cgrid, 256, 0, stream>>>(x1, wr2, b2, ss, x2, st + 128);
    finalize_kernel<<<1, 64, 0, stream>>>(st + 128, g2, be2, ss + 128, 64);
    conv_kernel<64,64,true,true,bf16,bf16><<<cgrid, 256, 0, stream>>>(x2, wr3, b3, ss + 128, x3, st + 256);
    finalize_kernel<<<1, 64, 0, stream>>>(st + 256, g3, be3, ss + 256, 64);
    bev_kernel<<<(OUTN_ + 255)/256, 256, 0, stream>>>(x3, ss + 256, out);
  } else if (ws_size >= needB){
    // ---- Plan B: x2 bf16 only ----
    float* parts = (float*)alloc(SPART);
    bf16*  x2    = (bf16*)alloc(SX2B);
    conv_kernel<1,32,false,false,float,bf16><<<cgrid, 256, 0, stream>>>(g0, wr1, b1, nullptr, (bf16*)nullptr, st);
    finalize_kernel<<<1, 64, 0, stream>>>(st, g1, be1, ss, 32);
    fused12_kernel<bf16><<<cgrid, 256, 0, stream>>>(g0, wr1, b1, ss, wr2, b2, x2, st + 128);
    finalize_kernel<<<1, 64, 0, stream>>>(st + 128, g2, be2, ss + 128, 64);
    conv_kernel<64,64,true,false,bf16,bf16><<<cgrid, 256, 0, stream>>>(x2, wr3, b3, ss + 128, (bf16*)nullptr, st + 256);
    finalize_kernel<<<1, 64, 0, stream>>>(st + 256, g3, be3, ss + 256, 64);
    conv3max_kernel<bf16,8><<<dim3(16, 16, 2), 256, 0, stream>>>(x2, wr3, b3, ss + 128, ss + 256, parts);
    maxreduce_kernel<<<(OUTN_ + 255)/256, 256, 0, stream>>>(parts, out, 16);
  } else {
    // ---- Plan C: x2 fp8 ----
    float* parts = (float*)alloc(SPART);
    fp8s*  x2    = (fp8s*)alloc(SX2C);
    conv_kernel<1,32,false,false,float,bf16><<<cgrid, 256, 0, stream>>>(g0, wr1, b1, nullptr, (bf16*)nullptr, st);
    finalize_kernel<<<1, 64, 0, stream>>>(st, g1, be1, ss, 32);
    fused12_kernel<fp8s><<<cgrid, 256, 0, stream>>>(g0, wr1, b1, ss, wr2, b2, x2, st + 128);
    finalize_kernel<<<1, 64, 0, stream>>>(st + 128, g2, be2, ss + 128, 64);
    conv_kernel<64,64,true,false,fp8s,bf16><<<cgrid, 256, 0, stream>>>(x2, wr3, b3, ss + 128, (bf16*)nullptr, st + 256);
    finalize_kernel<<<1, 64, 0, stream>>>(st + 256, g3, be3, ss + 256, 64);
    conv3max_kernel<fp8s,8><<<dim3(16, 16, 2), 256, 0, stream>>>(x2, wr3, b3, ss + 128, ss + 256, parts);
    maxreduce_kernel<<<(OUTN_ + 255)/256, 256, 0, stream>>>(parts, out, 16);
  }
}

// Round 6
// 6505.844 us; speedup vs baseline: 1.9657x; 1.9657x over previous
//
#include <hip/hip_runtime.h>
#include <hip/hip_bf16.h>
#include <float.h>

// LiDAR BEV pipeline (fp32 I/O):
//   voxelize -> conv3d(1->32)+BN+ReLU -> conv3d(32->64)+BN+ReLU -> conv3d(64->64)+BN+ReLU -> max over D
// R5 passed (12.79ms) via Plan B: conv3 ran TWICE (stats pass + max pass), conv3max at
// 40% VALUBusy / 12% occupancy. R6: single conv3 pass that accumulates BN3 stats AND
// per-D-slab min/max of raw y3 (monotonicity of z->relu(a*z+s) makes BN+ReLU+max exact
// from min/max), plus occupancy fix (4h x 32o blocks, min/max state in LDS not VGPRs).

#define VOXEL 0.0625f
#define D_ 128
#define H_ 128
#define W_ 32
#define HW_ (H_*W_)      // 4096
#define DHW_ (D_*H_*W_)  // 524288
#define B_ 2
#define EPSV 1e-5f
#define OUTN_ (B_*64*HW_) // 524288

typedef __hip_bfloat16 bf16;

// ---- fp8 e4m3fn storage (hand-rolled; only used by the small-ws plan) ----
struct fp8s { unsigned char v; };

__device__ inline float e4m3f(unsigned char c){
  int e = (c >> 3) & 0xF, m = c & 7;
  float x = e ? ldexpf((float)(8 + m), e - 10) : ldexpf((float)m, -9);
  return (c & 0x80) ? -x : x;
}
__device__ inline unsigned char f2e4m3(float x){
  unsigned u = __float_as_uint(x);
  unsigned s = (u >> 24) & 0x80u;
  float a = fabsf(x);
  if (a >= 448.f) return (unsigned char)(s | 0x7E);
  if (a < 0.015625f){
    int n = __float2int_rn(a * 512.f);
    return (unsigned char)(s | (unsigned)n);
  }
  unsigned b = __float_as_uint(a);
  b += 0x7FFFFu + ((b >> 20) & 1u);
  int e = (int)((b >> 23) & 0xFF) - 127;
  unsigned m = (b >> 20) & 7u;
  if (e > 8 || (e == 8 && m == 7)) return (unsigned char)(s | 0x7E);
  return (unsigned char)(s | ((unsigned)(e + 7) << 3) | m);
}

__device__ inline float ldf(const float* p){ return *p; }
__device__ inline float ldf(const bf16* p){ return __bfloat162float(*p); }
__device__ inline float ldf(const fp8s* p){ return e4m3f(p->v); }
__device__ inline void stf(float* p, float v){ *p = v; }
__device__ inline void stf(bf16* p, float v){ *p = __float2bfloat16(v); }
__device__ inline void stf(fp8s* p, float v){ p->v = f2e4m3(v); }

// ---------------- init ----------------

__global__ void zero_kernel(float* __restrict__ p, int n){
  int i = blockIdx.x*blockDim.x + threadIdx.x;
  if (i < n) p[i] = 0.f;
}

// ---------------- voxelize ----------------

__global__ void min_kernel(const float* __restrict__ pc, float* __restrict__ mins, int N){
  const float* base = pc + (size_t)blockIdx.x * N;
  float m = FLT_MAX;
  for (int j = threadIdx.x; j < N; j += blockDim.x){
    float v = base[j];
    if (v != v) v = 0.f;          // NaN -> 0, matching reference
    m = fminf(m, v);
  }
  for (int off = 32; off > 0; off >>= 1)
    m = fminf(m, __shfl_xor(m, off, 64));
  __shared__ float red[4];
  int wave = threadIdx.x >> 6;
  if ((threadIdx.x & 63) == 0) red[wave] = m;
  __syncthreads();
  if (threadIdx.x == 0){
    float r = red[0];
    for (int k = 1; k < (int)(blockDim.x >> 6); ++k) r = fminf(r, red[k]);
    mins[blockIdx.x] = r;
  }
}

__global__ void scatter_kernel(const float* __restrict__ pc, const float* __restrict__ mins,
                               float* __restrict__ grid, int N){
  int idx = blockIdx.x*blockDim.x + threadIdx.x;
  if (idx >= B_*N) return;
  int b = idx / N, n = idx - b*N;
  float x = pc[((size_t)b*3 + 0)*N + n];
  float y = pc[((size_t)b*3 + 1)*N + n];
  float z = pc[((size_t)b*3 + 2)*N + n];
  if (x != x) x = 0.f;
  if (y != y) y = 0.f;
  if (z != z) z = 0.f;
  int ix = (int)floorf((x - mins[b*3+0]) / VOXEL);
  int iy = (int)floorf((y - mins[b*3+1]) / VOXEL);
  int iz = (int)floorf((z - mins[b*3+2]) / VOXEL);
  ix = min(max(ix, 0), D_-1);
  iy = min(max(iy, 0), H_-1);
  iz = min(max(iz, 0), W_-1);
  grid[(size_t)b*DHW_ + (size_t)ix*HW_ + iy*W_ + iz] = 1.0f;
}

// ---------------- weight reorder: (O,I,3,3,3) -> (I,27,O) ----------------

__global__ void reorder_kernel(const float* __restrict__ w, float* __restrict__ wr, int CIN, int COUT){
  int idx = blockIdx.x*blockDim.x + threadIdx.x;
  int total = COUT*CIN*27;
  if (idx >= total) return;
  int o = idx / (CIN*27);
  int rem = idx - o*(CIN*27);
  int i = rem / 27;
  int k = rem - i*27;
  wr[(i*27 + k)*COUT + o] = w[idx];
}

// ---------------- shared conv inner: 27-tap accumulate from LDS tile ----------------
// 256 threads = 32 w-lanes x 8 o-groups; thread accumulates HT h x OPT o.

template<int HT, int OPT, int COUT>
__device__ inline void conv_inner(float (*xs)[HT+2][34], float (*wsm)[COUT],
                                  int w, int og, float (*acc)[OPT]){
  #pragma unroll
  for (int kd = 0; kd < 3; ++kd){
    float xr[HT+2][3];
    #pragma unroll
    for (int r = 0; r < HT+2; ++r)
      #pragma unroll
      for (int c = 0; c < 3; ++c)
        xr[r][c] = xs[kd][r][w + c];
    #pragma unroll
    for (int kh = 0; kh < 3; ++kh)
      #pragma unroll
      for (int kw = 0; kw < 3; ++kw){
        const float* wp = &wsm[kd*9 + kh*3 + kw][og*OPT];
        float wv[OPT];
        #pragma unroll
        for (int oo = 0; oo < OPT; ++oo) wv[oo] = wp[oo];
        #pragma unroll
        for (int h = 0; h < HT; ++h){
          float xv = xr[h + kh][kw];
          #pragma unroll
          for (int oo = 0; oo < OPT; ++oo)
            acc[h][oo] = fmaf(xv, wv[oo], acc[h][oo]);
        }
      }
  }
}

// ---------------- generic conv3d stats-only kernel (used for conv1 BN stats) ----------------

template<int CIN, int COUT, typename TIn>
__global__ __launch_bounds__(256)
void convstats_kernel(const TIn* __restrict__ X, const float* __restrict__ WR,
                      const float* __restrict__ bias, float* __restrict__ stats){
  constexpr int OPT = COUT / 8;
  const int tid = threadIdx.x;
  const int w   = tid & 31;
  const int og  = tid >> 5;
  const int h0  = blockIdx.x * 8;
  const int d   = blockIdx.y;
  const int b   = blockIdx.z;

  __shared__ float xs[3][10][34];
  __shared__ float wsm[27][COUT];

  float acc[8][OPT];
  #pragma unroll
  for (int h = 0; h < 8; ++h)
    #pragma unroll
    for (int oo = 0; oo < OPT; ++oo) acc[h][oo] = 0.f;

  for (int i = 0; i < CIN; ++i){
    __syncthreads();
    for (int e = tid; e < 27*COUT; e += 256)
      ((float*)wsm)[e] = WR[i*27*COUT + e];
    for (int e = tid; e < 960; e += 256){
      int ds = e / 320; int rem = e - ds*320; int r = rem >> 5; int ww = rem & 31;
      int dd = d + ds - 1, hh = h0 + r - 1;
      float v = 0.f;
      if (dd >= 0 && dd < D_ && hh >= 0 && hh < H_)
        v = ldf(&X[((size_t)(b*CIN + i)*D_ + dd)*HW_ + hh*W_ + ww]);
      xs[ds][r][ww + 1] = v;
    }
    if (tid < 30){ int ds = tid/10, r = tid - ds*10; xs[ds][r][0] = 0.f; xs[ds][r][33] = 0.f; }
    __syncthreads();
    conv_inner<8, OPT, COUT>(xs, wsm, w, og, acc);
  }

  #pragma unroll
  for (int oo = 0; oo < OPT; ++oo){
    int o = og*OPT + oo;
    float bo = bias[o];
    float s1 = 0.f, s2 = 0.f;
    #pragma unroll
    for (int h = 0; h < 8; ++h){
      float y = acc[h][oo] + bo;
      s1 += y;
      s2 = fmaf(y, y, s2);
    }
    for (int m = 16; m > 0; m >>= 1){
      s1 += __shfl_xor(s1, m, 32);
      s2 += __shfl_xor(s2, m, 32);
    }
    if (w == 0){
      atomicAdd(&stats[o], s1);
      atomicAdd(&stats[COUT + o], s2);
    }
  }
}

// ---------------- fused conv1(1->32)+BN1+ReLU + conv2(32->64): recomputes conv1 per tile ----------------

template<typename TOut>
__global__ __launch_bounds__(256)
void fused12_kernel(const float* __restrict__ G0, const float* __restrict__ WR1,
                    const float* __restrict__ B1, const float* __restrict__ SS1,
                    const float* __restrict__ WR2, const float* __restrict__ B2,
                    TOut* __restrict__ X2, float* __restrict__ stats){
  const int tid = threadIdx.x;
  const int w   = tid & 31;
  const int og  = tid >> 5;
  const int h0  = blockIdx.x * 8;
  const int d   = blockIdx.y;
  const int b   = blockIdx.z;

  __shared__ float gs[5][12][34];    // occupancy tile (+2 halo in d/h, +1 in w)
  __shared__ float w1s[32][27];
  __shared__ float xs[3][10][34];    // x1 channel tile, post BN1+ReLU
  __shared__ float wsm[27][64];

  for (int e = tid; e < 5*12*34; e += 256){
    int ds = e / 408; int rem = e - ds*408; int r = rem / 34; int c = rem - r*34;
    int dd = d - 2 + ds, hh = h0 - 2 + r, ww = c - 1;
    float v = 0.f;
    if (c >= 1 && c <= 32 && dd >= 0 && dd < D_ && hh >= 0 && hh < H_)
      v = G0[((size_t)b*D_ + dd)*HW_ + hh*W_ + ww];
    gs[ds][r][c] = v;
  }
  for (int e = tid; e < 864; e += 256){
    int i = e/27, k = e - 27*i;
    w1s[i][k] = WR1[k*32 + i];
  }

  float acc[8][8];
  #pragma unroll
  for (int h = 0; h < 8; ++h)
    #pragma unroll
    for (int oo = 0; oo < 8; ++oo) acc[h][oo] = 0.f;

  for (int i = 0; i < 32; ++i){
    __syncthreads();
    float a1 = SS1[i];
    float f1 = fmaf(a1, B1[i], SS1[32 + i]);   // a1*b1 + shift1
    for (int e = tid; e < 1020; e += 256){
      int ds = e / 340; int rem = e - ds*340; int r = rem / 34; int c = rem - r*34;
      float v = 0.f;
      int dd = d - 1 + ds, hh = h0 - 1 + r;
      if (c >= 1 && c <= 32 && dd >= 0 && dd < D_ && hh >= 0 && hh < H_){
        float s = 0.f;
        #pragma unroll
        for (int kd = 0; kd < 3; ++kd)
          #pragma unroll
          for (int kh = 0; kh < 3; ++kh)
            #pragma unroll
            for (int kw = 0; kw < 3; ++kw)
              s = fmaf(gs[ds+kd][r+kh][c-1+kw], w1s[i][kd*9+kh*3+kw], s);
        v = fmaxf(fmaf(a1, s, f1), 0.f);
      }
      xs[ds][r][c] = v;
    }
    for (int e = tid; e < 27*64; e += 256)
      ((float*)wsm)[e] = WR2[i*27*64 + e];
    __syncthreads();
    conv_inner<8, 8, 64>(xs, wsm, w, og, acc);
  }

  #pragma unroll
  for (int oo = 0; oo < 8; ++oo){
    int o = og*8 + oo;
    float bo = B2[o];
    float s1 = 0.f, s2 = 0.f;
    #pragma unroll
    for (int h = 0; h < 8; ++h){
      float y = acc[h][oo] + bo;
      stf(&X2[((size_t)(b*64 + o)*D_ + d)*HW_ + (h0 + h)*W_ + w], y);
      s1 += y;
      s2 = fmaf(y, y, s2);
    }
    for (int m = 16; m > 0; m >>= 1){
      s1 += __shfl_xor(s1, m, 32);
      s2 += __shfl_xor(s2, m, 32);
    }
    if (w == 0){
      atomicAdd(&stats[o], s1);
      atomicAdd(&stats[64 + o], s2);
    }
  }
}

// ---------------- conv3 single pass: BN2 on input, accumulate BN3 stats, per-slab min/max of raw y3 ----------------
// Block: 4h x 32w x 32o (o-half), DCHUNK d's. min/max state lives in LDS (owner-exclusive
// cells) to keep VGPRs ~80 -> high occupancy. bf16 min/max == min/max then round (monotone).

template<typename TIn, int DCHUNK, int HT>
__global__ __launch_bounds__(256, 4)
void conv3mm_kernel(const TIn* __restrict__ X, const float* __restrict__ WR,
                    const float* __restrict__ bias, const float* __restrict__ ssIn,
                    float* __restrict__ stats, bf16* __restrict__ minp, bf16* __restrict__ maxp){
  const int tid = threadIdx.x;
  const int w   = tid & 31;
  const int og  = tid >> 5;                 // 0..7
  constexpr int NHT = H_ / HT;              // 32
  const int hb  = blockIdx.x % NHT;
  const int oh  = blockIdx.x / NHT;         // 0/1 (which 32-channel half)
  const int h0  = hb * HT;
  const int d0  = blockIdx.y * DCHUNK;
  const int b   = blockIdx.z;

  __shared__ float xs[3][HT+2][34];
  __shared__ float wsm[27][32];
  __shared__ bf16  bmm[2][HT][32][32];      // [0]=max, [1]=min; [h][o_local][w]

  for (int e = tid; e < 2*HT*32*32; e += 256)
    ((bf16*)bmm)[e] = __float2bfloat16(e < HT*32*32 ? -FLT_MAX : FLT_MAX);  // rounds to -/+inf, fine

  float br[4], psum[4], psq[4];
  #pragma unroll
  for (int oo = 0; oo < 4; ++oo){
    br[oo] = bias[oh*32 + og*4 + oo];
    psum[oo] = 0.f; psq[oo] = 0.f;
  }

  for (int d = d0; d < d0 + DCHUNK; ++d){
    float acc[HT][4];
    #pragma unroll
    for (int h = 0; h < HT; ++h)
      #pragma unroll
      for (int oo = 0; oo < 4; ++oo) acc[h][oo] = 0.f;

    for (int i = 0; i < 64; ++i){
      __syncthreads();
      for (int e = tid; e < 27*32; e += 256){
        int k = e >> 5, oc = e & 31;
        wsm[k][oc] = WR[(i*27 + k)*64 + oh*32 + oc];
      }
      float a_ = ssIn[i], s_ = ssIn[64 + i];
      for (int e = tid; e < 3*(HT+2)*32; e += 256){
        int ds = e / ((HT+2)*32); int rem = e - ds*(HT+2)*32; int r = rem >> 5; int ww = rem & 31;
        int dd = d + ds - 1, hh = h0 + r - 1;
        float v = 0.f;
        if (dd >= 0 && dd < D_ && hh >= 0 && hh < H_){
          v = ldf(&X[((size_t)(b*64 + i)*D_ + dd)*HW_ + hh*W_ + ww]);
          v = fmaxf(fmaf(a_, v, s_), 0.f);
        }
        xs[ds][r][ww + 1] = v;
      }
      if (tid < 3*(HT+2)){ int ds = tid/(HT+2), r = tid - ds*(HT+2); xs[ds][r][0] = 0.f; xs[ds][r][33] = 0.f; }
      __syncthreads();
      conv_inner<HT, 4, 32>(xs, wsm, w, og, acc);
    }

    // per-d epilogue: stats + LDS min/max update (owner-exclusive cells, fenced by the
    // __syncthreads inside the i-loop so values can't be register-hoisted across d)
    #pragma unroll
    for (int oo = 0; oo < 4; ++oo){
      int ol = og*4 + oo;
      #pragma unroll
      for (int h = 0; h < HT; ++h){
        float y = acc[h][oo] + br[oo];
        psum[oo] += y;
        psq[oo]  = fmaf(y, y, psq[oo]);
        float cmx = ldf(&bmm[0][h][ol][w]);
        if (y > cmx) stf(&bmm[0][h][ol][w], y);
        float cmn = ldf(&bmm[1][h][ol][w]);
        if (y < cmn) stf(&bmm[1][h][ol][w], y);
      }
    }
  }

  // stats: reduce over the 32 w-lanes, one atomic per (block, o)
  #pragma unroll
  for (int oo = 0; oo < 4; ++oo){
    float s1 = psum[oo], s2 = psq[oo];
    for (int m = 16; m > 0; m >>= 1){
      s1 += __shfl_xor(s1, m, 32);
      s2 += __shfl_xor(s2, m, 32);
    }
    if (w == 0){
      int o = oh*32 + og*4 + oo;
      atomicAdd(&stats[o], s1);
      atomicAdd(&stats[64 + o], s2);
    }
  }

  // dump LDS min/max to the slab partials
  __syncthreads();
  const size_t slab = (size_t)blockIdx.y * OUTN_;
  for (int e = tid; e < 2*HT*32*32; e += 256){
    int mm = e / (HT*32*32); int rem = e % (HT*32*32);
    int h = rem >> 10; int ol = (rem >> 5) & 31; int ww = rem & 31;
    bf16* dst = mm ? minp : maxp;
    dst[slab + ((size_t)(b*64 + oh*32 + ol))*HW_ + (h0 + h)*W_ + ww] = ((bf16*)bmm)[e];
  }
}

// ---------------- final: reduce slabs, apply BN3+ReLU via monotonicity ----------------

__global__ void bevreduce_kernel(const bf16* __restrict__ minp, const bf16* __restrict__ maxp,
                                 const float* __restrict__ ss, float* __restrict__ out, int nslab){
  int j = blockIdx.x*blockDim.x + threadIdx.x;
  if (j >= OUTN_) return;
  int o = (j >> 12) & 63;
  float mx = -FLT_MAX, mn = FLT_MAX;
  for (int s = 0; s < nslab; ++s){
    mx = fmaxf(mx, __bfloat162float(maxp[(size_t)s*OUTN_ + j]));
    mn = fminf(mn, __bfloat162float(minp[(size_t)s*OUTN_ + j]));
  }
  float a = ss[o], sh = ss[64 + o];
  float v = (a >= 0.f) ? mx : mn;   // relu(a*z+s) is monotone in z with direction sign(a)
  out[j] = fmaxf(fmaf(a, v, sh), 0.f);
}

// ---------------- BN finalize: scale = g*rsqrt(var+eps), shift = beta - mean*scale ----------------

__global__ void finalize_kernel(const float* __restrict__ stats, const float* __restrict__ gamma,
                                const float* __restrict__ beta, float* __restrict__ ss, int C){
  int c = threadIdx.x;
  if (c >= C) return;
  const float invCnt = 1.0f / (float)((size_t)B_*DHW_);
  float mean = stats[c] * invCnt;
  float var  = stats[C + c] * invCnt - mean*mean;
  float a = gamma[c] * rsqrtf(var + EPSV);
  ss[c]     = a;
  ss[C + c] = beta[c] - mean*a;
}

// ---------------- launch ----------------

extern "C" void kernel_launch(void* const* d_in, const int* in_sizes, int n_in,
                              void* d_out, int out_size, void* d_ws, size_t ws_size,
                              hipStream_t stream){
  const float* pc  = (const float*)d_in[0];
  const float* w1  = (const float*)d_in[1];
  const float* b1  = (const float*)d_in[2];
  const float* g1  = (const float*)d_in[3];
  const float* be1 = (const float*)d_in[4];
  const float* w2  = (const float*)d_in[5];
  const float* b2  = (const float*)d_in[6];
  const float* g2  = (const float*)d_in[7];
  const float* be2 = (const float*)d_in[8];
  const float* w3  = (const float*)d_in[9];
  const float* b3  = (const float*)d_in[10];
  const float* g3  = (const float*)d_in[11];
  const float* be3 = (const float*)d_in[12];
  const int N = in_sizes[0] / 6;  // (B=2, 3, N)
  float* out = (float*)d_out;

  char* wsb = (char*)d_ws;
  size_t off = 0;
  auto alloc = [&](size_t bytes)->char*{
    off = (off + 255) & ~(size_t)255;
    char* p = wsb + off; off += bytes; return p;
  };
  float* g0  = (float*)alloc((size_t)B_*DHW_*4);   // 4 MB
  float* wr1 = (float*)alloc(864*4);
  float* wr2 = (float*)alloc(55296*4);
  float* wr3 = (float*)alloc(110592*4);
  float* mins= (float*)alloc(8*4);
  float* st  = (float*)alloc(3*128*4);
  float* ss  = (float*)alloc(3*128*4);

  constexpr int DCHUNK = 8;
  constexpr int NSLAB  = D_ / DCHUNK;          // 16
  const size_t SX2B  = (size_t)B_*64*DHW_*2;   // 128 MiB bf16
  const size_t SX2C  = (size_t)B_*64*DHW_;     // 64 MiB fp8
  const size_t SMM   = (size_t)NSLAB*OUTN_*2;  // 16 MiB per min/max array (bf16)
  const size_t prefix = (off + 255) & ~(size_t)255;
  const size_t needB = prefix + 2*SMM + SX2B + 3*256;

  bf16* maxp = (bf16*)alloc(SMM);
  bf16* minp = (bf16*)alloc(SMM);

  // common prologue
  zero_kernel<<<(B_*DHW_ + 255)/256, 256, 0, stream>>>(g0, B_*DHW_);
  zero_kernel<<<2, 256, 0, stream>>>(st, 3*128);
  min_kernel<<<B_*3, 256, 0, stream>>>(pc, mins, N);
  scatter_kernel<<<(B_*N + 255)/256, 256, 0, stream>>>(pc, mins, g0, N);
  reorder_kernel<<<(864 + 255)/256, 256, 0, stream>>>(w1, wr1, 1, 32);
  reorder_kernel<<<(55296 + 255)/256, 256, 0, stream>>>(w2, wr2, 32, 64);
  reorder_kernel<<<(110592 + 255)/256, 256, 0, stream>>>(w3, wr3, 64, 64);

  dim3 cgrid(16, 128, 2);                      // (8h-tiles, d, b) for conv1/fused12
  dim3 mmgrid(2*(H_/4), NSLAB, 2);             // (4h-tiles x 2 o-halves, slabs, b) = (64,16,2)

  // conv1 BN stats (CIN=1, cheap)
  convstats_kernel<1,32,float><<<cgrid, 256, 0, stream>>>(g0, wr1, b1, st);
  finalize_kernel<<<1, 64, 0, stream>>>(st, g1, be1, ss, 32);

  if (ws_size >= needB){
    // x2 stored bf16
    bf16* x2 = (bf16*)alloc(SX2B);
    fused12_kernel<bf16><<<cgrid, 256, 0, stream>>>(g0, wr1, b1, ss, wr2, b2, x2, st + 128);
    finalize_kernel<<<1, 64, 0, stream>>>(st + 128, g2, be2, ss + 128, 64);
    conv3mm_kernel<bf16,DCHUNK,4><<<mmgrid, 256, 0, stream>>>(x2, wr3, b3, ss + 128, st + 256, minp, maxp);
  } else {
    // x2 stored fp8 e4m3
    fp8s* x2 = (fp8s*)alloc(SX2C);
    fused12_kernel<fp8s><<<cgrid, 256, 0, stream>>>(g0, wr1, b1, ss, wr2, b2, x2, st + 128);
    finalize_kernel<<<1, 64, 0, stream>>>(st + 128, g2, be2, ss + 128, 64);
    conv3mm_kernel<fp8s,DCHUNK,4><<<mmgrid, 256, 0, stream>>>(x2, wr3, b3, ss + 128, st + 256, minp, maxp);
  }
  finalize_kernel<<<1, 64, 0, stream>>>(st + 256, g3, be3, ss + 256, 64);
  bevreduce_kernel<<<(OUTN_ + 255)/256, 256, 0, stream>>>(minp, maxp, ss + 256, out, NSLAB);
}

// Round 7
// 4134.029 us; speedup vs baseline: 3.0935x; 1.5737x over previous
//
#include <hip/hip_runtime.h>
#include <hip/hip_bf16.h>
#include <float.h>

// LiDAR BEV pipeline (fp32 I/O):
//   voxelize -> conv3d(1->32)+BN+ReLU -> conv3d(32->64)+BN+ReLU -> conv3d(64->64)+BN+ReLU -> max over D
// R6: 6.51ms, conv3 fp32 VALU-bound (83% VALUBusy, MfmaUtil 0). R7: conv3 as MFMA
// implicit-GEMM (bf16 16x16x32): A = shifted ds_read_b128 from halo-ed channel-last LDS
// tile; B = weight fragments straight from L1/L2 (reordered [tap][o][i] bf16);
// BN2 folded into A-staging; BN3 stats + per-(w,o) min/max of raw y3 in VGPRs ->
// slab partials -> exact BN3+ReLU+max via monotonicity (R6 scheme).

#define VOXEL 0.0625f
#define D_ 128
#define H_ 128
#define W_ 32
#define HW_ (H_*W_)      // 4096
#define DHW_ (D_*H_*W_)  // 524288
#define B_ 2
#define EPSV 1e-5f
#define OUTN_ (B_*64*HW_) // 524288

typedef __hip_bfloat16 bf16;
typedef __attribute__((ext_vector_type(8))) short short8;   // 8 bf16 (4 VGPRs)
typedef __attribute__((ext_vector_type(4))) float f32x4;

// ---- fp8 e4m3fn storage (small-ws fallback) ----
struct fp8s { unsigned char v; };

__device__ inline float e4m3f(unsigned char c){
  int e = (c >> 3) & 0xF, m = c & 7;
  float x = e ? ldexpf((float)(8 + m), e - 10) : ldexpf((float)m, -9);
  return (c & 0x80) ? -x : x;
}
__device__ inline unsigned char f2e4m3(float x){
  unsigned u = __float_as_uint(x);
  unsigned s = (u >> 24) & 0x80u;
  float a = fabsf(x);
  if (a >= 448.f) return (unsigned char)(s | 0x7E);
  if (a < 0.015625f){
    int n = __float2int_rn(a * 512.f);
    return (unsigned char)(s | (unsigned)n);
  }
  unsigned b = __float_as_uint(a);
  b += 0x7FFFFu + ((b >> 20) & 1u);
  int e = (int)((b >> 23) & 0xFF) - 127;
  unsigned m = (b >> 20) & 7u;
  if (e > 8 || (e == 8 && m == 7)) return (unsigned char)(s | 0x7E);
  return (unsigned char)(s | ((unsigned)(e + 7) << 3) | m);
}

__device__ inline float ldf(const float* p){ return *p; }
__device__ inline float ldf(const bf16* p){ return __bfloat162float(*p); }
__device__ inline float ldf(const fp8s* p){ return e4m3f(p->v); }
__device__ inline void stf(float* p, float v){ *p = v; }
__device__ inline void stf(bf16* p, float v){ *p = __float2bfloat16(v); }
__device__ inline void stf(fp8s* p, float v){ p->v = f2e4m3(v); }

// ---------------- init ----------------

__global__ void zero_kernel(float* __restrict__ p, int n){
  int i = blockIdx.x*blockDim.x + threadIdx.x;
  if (i < n) p[i] = 0.f;
}

// ---------------- voxelize ----------------

__global__ void min_kernel(const float* __restrict__ pc, float* __restrict__ mins, int N){
  const float* base = pc + (size_t)blockIdx.x * N;
  float m = FLT_MAX;
  for (int j = threadIdx.x; j < N; j += blockDim.x){
    float v = base[j];
    if (v != v) v = 0.f;          // NaN -> 0, matching reference
    m = fminf(m, v);
  }
  for (int off = 32; off > 0; off >>= 1)
    m = fminf(m, __shfl_xor(m, off, 64));
  __shared__ float red[4];
  int wave = threadIdx.x >> 6;
  if ((threadIdx.x & 63) == 0) red[wave] = m;
  __syncthreads();
  if (threadIdx.x == 0){
    float r = red[0];
    for (int k = 1; k < (int)(blockDim.x >> 6); ++k) r = fminf(r, red[k]);
    mins[blockIdx.x] = r;
  }
}

__global__ void scatter_kernel(const float* __restrict__ pc, const float* __restrict__ mins,
                               float* __restrict__ grid, int N){
  int idx = blockIdx.x*blockDim.x + threadIdx.x;
  if (idx >= B_*N) return;
  int b = idx / N, n = idx - b*N;
  float x = pc[((size_t)b*3 + 0)*N + n];
  float y = pc[((size_t)b*3 + 1)*N + n];
  float z = pc[((size_t)b*3 + 2)*N + n];
  if (x != x) x = 0.f;
  if (y != y) y = 0.f;
  if (z != z) z = 0.f;
  int ix = (int)floorf((x - mins[b*3+0]) / VOXEL);
  int iy = (int)floorf((y - mins[b*3+1]) / VOXEL);
  int iz = (int)floorf((z - mins[b*3+2]) / VOXEL);
  ix = min(max(ix, 0), D_-1);
  iy = min(max(iy, 0), H_-1);
  iz = min(max(iz, 0), W_-1);
  grid[(size_t)b*DHW_ + (size_t)ix*HW_ + iy*W_ + iz] = 1.0f;
}

// ---------------- weight reorders ----------------

__global__ void reorder_kernel(const float* __restrict__ w, float* __restrict__ wr, int CIN, int COUT){
  int idx = blockIdx.x*blockDim.x + threadIdx.x;
  int total = COUT*CIN*27;
  if (idx >= total) return;
  int o = idx / (CIN*27);
  int rem = idx - o*(CIN*27);
  int i = rem / 27;
  int k = rem - i*27;
  wr[(i*27 + k)*COUT + o] = w[idx];
}

// w3 (64,64,3,3,3) fp32 -> [tap][o][i] bf16 for MFMA B-fragments
__global__ void reorder3b_kernel(const float* __restrict__ w, bf16* __restrict__ wb){
  int idx = blockIdx.x*blockDim.x + threadIdx.x;
  if (idx >= 64*64*27) return;
  int o = idx / (64*27);
  int rem = idx - o*(64*27);
  int i = rem / 27;
  int tap = rem - i*27;
  wb[((size_t)tap*64 + o)*64 + i] = __float2bfloat16(w[idx]);
}

// ---------------- fp32 conv inner (kept for conv1/fused12) ----------------

template<int HT, int OPT, int COUT>
__device__ inline void conv_inner(float (*xs)[HT+2][34], float (*wsm)[COUT],
                                  int w, int og, float (*acc)[OPT]){
  #pragma unroll
  for (int kd = 0; kd < 3; ++kd){
    float xr[HT+2][3];
    #pragma unroll
    for (int r = 0; r < HT+2; ++r)
      #pragma unroll
      for (int c = 0; c < 3; ++c)
        xr[r][c] = xs[kd][r][w + c];
    #pragma unroll
    for (int kh = 0; kh < 3; ++kh)
      #pragma unroll
      for (int kw = 0; kw < 3; ++kw){
        const float* wp = &wsm[kd*9 + kh*3 + kw][og*OPT];
        float wv[OPT];
        #pragma unroll
        for (int oo = 0; oo < OPT; ++oo) wv[oo] = wp[oo];
        #pragma unroll
        for (int h = 0; h < HT; ++h){
          float xv = xr[h + kh][kw];
          #pragma unroll
          for (int oo = 0; oo < OPT; ++oo)
            acc[h][oo] = fmaf(xv, wv[oo], acc[h][oo]);
        }
      }
  }
}

// ---------------- conv1 BN stats (CIN=1, cheap) ----------------

template<int CIN, int COUT, typename TIn>
__global__ __launch_bounds__(256)
void convstats_kernel(const TIn* __restrict__ X, const float* __restrict__ WR,
                      const float* __restrict__ bias, float* __restrict__ stats){
  constexpr int OPT = COUT / 8;
  const int tid = threadIdx.x;
  const int w   = tid & 31;
  const int og  = tid >> 5;
  const int h0  = blockIdx.x * 8;
  const int d   = blockIdx.y;
  const int b   = blockIdx.z;

  __shared__ float xs[3][10][34];
  __shared__ float wsm[27][COUT];

  float acc[8][OPT];
  #pragma unroll
  for (int h = 0; h < 8; ++h)
    #pragma unroll
    for (int oo = 0; oo < OPT; ++oo) acc[h][oo] = 0.f;

  for (int i = 0; i < CIN; ++i){
    __syncthreads();
    for (int e = tid; e < 27*COUT; e += 256)
      ((float*)wsm)[e] = WR[i*27*COUT + e];
    for (int e = tid; e < 960; e += 256){
      int ds = e / 320; int rem = e - ds*320; int r = rem >> 5; int ww = rem & 31;
      int dd = d + ds - 1, hh = h0 + r - 1;
      float v = 0.f;
      if (dd >= 0 && dd < D_ && hh >= 0 && hh < H_)
        v = ldf(&X[((size_t)(b*CIN + i)*D_ + dd)*HW_ + hh*W_ + ww]);
      xs[ds][r][ww + 1] = v;
    }
    if (tid < 30){ int ds = tid/10, r = tid - ds*10; xs[ds][r][0] = 0.f; xs[ds][r][33] = 0.f; }
    __syncthreads();
    conv_inner<8, OPT, COUT>(xs, wsm, w, og, acc);
  }

  #pragma unroll
  for (int oo = 0; oo < OPT; ++oo){
    int o = og*OPT + oo;
    float bo = bias[o];
    float s1 = 0.f, s2 = 0.f;
    #pragma unroll
    for (int h = 0; h < 8; ++h){
      float y = acc[h][oo] + bo;
      s1 += y;
      s2 = fmaf(y, y, s2);
    }
    for (int m = 16; m > 0; m >>= 1){
      s1 += __shfl_xor(s1, m, 32);
      s2 += __shfl_xor(s2, m, 32);
    }
    if (w == 0){
      atomicAdd(&stats[o], s1);
      atomicAdd(&stats[COUT + o], s2);
    }
  }
}

// ---------------- fused conv1+BN1+ReLU + conv2 (fp32, recompute conv1 per tile) ----------------

template<typename TOut>
__global__ __launch_bounds__(256)
void fused12_kernel(const float* __restrict__ G0, const float* __restrict__ WR1,
                    const float* __restrict__ B1, const float* __restrict__ SS1,
                    const float* __restrict__ WR2, const float* __restrict__ B2,
                    TOut* __restrict__ X2, float* __restrict__ stats){
  const int tid = threadIdx.x;
  const int w   = tid & 31;
  const int og  = tid >> 5;
  const int h0  = blockIdx.x * 8;
  const int d   = blockIdx.y;
  const int b   = blockIdx.z;

  __shared__ float gs[5][12][34];
  __shared__ float w1s[32][27];
  __shared__ float xs[3][10][34];
  __shared__ float wsm[27][64];

  for (int e = tid; e < 5*12*34; e += 256){
    int ds = e / 408; int rem = e - ds*408; int r = rem / 34; int c = rem - r*34;
    int dd = d - 2 + ds, hh = h0 - 2 + r, ww = c - 1;
    float v = 0.f;
    if (c >= 1 && c <= 32 && dd >= 0 && dd < D_ && hh >= 0 && hh < H_)
      v = G0[((size_t)b*D_ + dd)*HW_ + hh*W_ + ww];
    gs[ds][r][c] = v;
  }
  for (int e = tid; e < 864; e += 256){
    int i = e/27, k = e - 27*i;
    w1s[i][k] = WR1[k*32 + i];
  }

  float acc[8][8];
  #pragma unroll
  for (int h = 0; h < 8; ++h)
    #pragma unroll
    for (int oo = 0; oo < 8; ++oo) acc[h][oo] = 0.f;

  for (int i = 0; i < 32; ++i){
    __syncthreads();
    float a1 = SS1[i];
    float f1 = fmaf(a1, B1[i], SS1[32 + i]);
    for (int e = tid; e < 1020; e += 256){
      int ds = e / 340; int rem = e - ds*340; int r = rem / 34; int c = rem - r*34;
      float v = 0.f;
      int dd = d - 1 + ds, hh = h0 - 1 + r;
      if (c >= 1 && c <= 32 && dd >= 0 && dd < D_ && hh >= 0 && hh < H_){
        float s = 0.f;
        #pragma unroll
        for (int kd = 0; kd < 3; ++kd)
          #pragma unroll
          for (int kh = 0; kh < 3; ++kh)
            #pragma unroll
            for (int kw = 0; kw < 3; ++kw)
              s = fmaf(gs[ds+kd][r+kh][c-1+kw], w1s[i][kd*9+kh*3+kw], s);
        v = fmaxf(fmaf(a1, s, f1), 0.f);
      }
      xs[ds][r][c] = v;
    }
    for (int e = tid; e < 27*64; e += 256)
      ((float*)wsm)[e] = WR2[i*27*64 + e];
    __syncthreads();
    conv_inner<8, 8, 64>(xs, wsm, w, og, acc);
  }

  #pragma unroll
  for (int oo = 0; oo < 8; ++oo){
    int o = og*8 + oo;
    float bo = B2[o];
    float s1 = 0.f, s2 = 0.f;
    #pragma unroll
    for (int h = 0; h < 8; ++h){
      float y = acc[h][oo] + bo;
      stf(&X2[((size_t)(b*64 + o)*D_ + d)*HW_ + (h0 + h)*W_ + w], y);
      s1 += y;
      s2 = fmaf(y, y, s2);
    }
    for (int m = 16; m > 0; m >>= 1){
      s1 += __shfl_xor(s1, m, 32);
      s2 += __shfl_xor(s2, m, 32);
    }
    if (w == 0){
      atomicAdd(&stats[o], s1);
      atomicAdd(&stats[64 + o], s2);
    }
  }
}

// ---------------- conv3 MFMA implicit-GEMM + BN3 stats + per-(w,o) min/max over d ----------------
// Block: 4 h-rows x 32 w x 64 o; wave wv owns h-row h0+wv, M=32 (2 m-tiles) x N=64 (4 n-tiles).
// K-step = (tap, ic): A-frag = shifted ds_read_b128 from halo tile [kd][io][r][w'][8ch];
// B-frag = global dwordx4 from [tap][o][i] bf16 (L1-hot). 8 MFMA per K-step per wave.

template<typename TIn, int DCHUNK>
__global__ __launch_bounds__(256, 2)
void conv3mfma_kernel(const TIn* __restrict__ X, const bf16* __restrict__ WB,
                      const float* __restrict__ bias, const float* __restrict__ ssIn,
                      float* __restrict__ stats, bf16* __restrict__ minp, bf16* __restrict__ maxp){
  const int tid  = threadIdx.x;
  const int lane = tid & 63;
  const int wv   = tid >> 6;        // wave id = h-row 0..3
  const int l15  = lane & 15;
  const int quad = lane >> 4;       // 0..3
  const int h0   = blockIdx.x * 4;
  const int d0   = blockIdx.y * DCHUNK;
  const int b    = blockIdx.z;

  __shared__ __align__(16) bf16 at[3][4][6][34][8];   // [kd][io][r][w'][cl], 38.3 KB

  // zero the w-halo columns once (w'=0 and 33 are the W-boundary SAME-pad: always 0)
  for (int e = tid; e < 3*4*6*2*8; e += 256){
    int cl = e & 7; int side = (e >> 3) & 1; int r = (e >> 4) % 6; int rest = (e >> 4) / 6;
    int io = rest & 3; int ds = rest >> 2;
    at[ds][io][r][side ? 33 : 0][cl] = __float2bfloat16(0.f);
  }

  f32x4 acc[2][4];
  float mmx[2][4][4], mmn[2][4][4];
  float brg[4];
  #pragma unroll
  for (int nt = 0; nt < 4; ++nt) brg[nt] = bias[nt*16 + l15];
  #pragma unroll
  for (int mh = 0; mh < 2; ++mh)
    #pragma unroll
    for (int nt = 0; nt < 4; ++nt)
      #pragma unroll
      for (int rg = 0; rg < 4; ++rg){ mmx[mh][nt][rg] = -FLT_MAX; mmn[mh][nt][rg] = FLT_MAX; }
  float psum[4] = {0.f,0.f,0.f,0.f}, psq[4] = {0.f,0.f,0.f,0.f};

  for (int d = d0; d < d0 + DCHUNK; ++d){
    #pragma unroll
    for (int mh = 0; mh < 2; ++mh)
      #pragma unroll
      for (int nt = 0; nt < 4; ++nt)
        acc[mh][nt] = (f32x4){0.f, 0.f, 0.f, 0.f};

    for (int ic = 0; ic < 2; ++ic){
      __syncthreads();
      // stage: 3 d-slices x 6 h-rows x 32 w x 32 ch (pairs of channels per thread)
      for (int e = tid; e < 9216; e += 256){
        int w = e & 31, cp = (e >> 5) & 15, rr = e >> 9;   // rr in [0,18)
        int ds = rr / 6, r = rr % 6;
        int c = cp * 2;
        int dd = d + ds - 1, hh = h0 + r - 1;
        float v0 = 0.f, v1 = 0.f;
        if (dd >= 0 && dd < D_ && hh >= 0 && hh < H_){
          int cg = ic*32 + c;
          size_t base = ((size_t)(b*64 + cg)*D_ + dd)*HW_ + hh*W_ + w;
          float x0 = ldf(&X[base]);
          float x1 = ldf(&X[base + (size_t)DHW_]);
          v0 = fmaxf(fmaf(ssIn[cg],     x0, ssIn[64 + cg]),     0.f);
          v1 = fmaxf(fmaf(ssIn[cg + 1], x1, ssIn[64 + cg + 1]), 0.f);
        }
        bf16 b2[2] = { __float2bfloat16(v0), __float2bfloat16(v1) };
        *(unsigned*)&at[ds][c >> 3][r][w + 1][c & 7] = *(unsigned*)b2;
      }
      __syncthreads();

      // 27 taps = 27 K-steps of K=32
      #pragma unroll
      for (int kd = 0; kd < 3; ++kd)
        #pragma unroll
        for (int kh = 0; kh < 3; ++kh)
          #pragma unroll
          for (int kw = 0; kw < 3; ++kw){
            short8 af[2], bfr[4];
            #pragma unroll
            for (int mh = 0; mh < 2; ++mh)
              af[mh] = *(const short8*)&at[kd][quad][wv + kh][mh*16 + l15 + kw][0];
            const bf16* wb = WB + (size_t)((kd*3 + kh)*3 + kw)*64*64 + ic*32 + quad*8;
            #pragma unroll
            for (int nt = 0; nt < 4; ++nt)
              bfr[nt] = *(const short8*)(wb + (nt*16 + l15)*64);
            #pragma unroll
            for (int mh = 0; mh < 2; ++mh)
              #pragma unroll
              for (int nt = 0; nt < 4; ++nt)
                acc[mh][nt] = __builtin_amdgcn_mfma_f32_16x16x32_bf16(af[mh], bfr[nt], acc[mh][nt], 0, 0, 0);
          }
    }

    // per-d epilogue: bias, stats partials, min/max in VGPRs (lane<->(w,o) fixed)
    #pragma unroll
    for (int mh = 0; mh < 2; ++mh)
      #pragma unroll
      for (int nt = 0; nt < 4; ++nt)
        #pragma unroll
        for (int rg = 0; rg < 4; ++rg){
          float y = acc[mh][nt][rg] + brg[nt];
          psum[nt] += y;
          psq[nt]  = fmaf(y, y, psq[nt]);
          mmx[mh][nt][rg] = fmaxf(mmx[mh][nt][rg], y);
          mmn[mh][nt][rg] = fminf(mmn[mh][nt][rg], y);
        }
  }

  // BN3 stats: lanes {l, l+16, l+32, l+48} share o = nt*16 + l15
  #pragma unroll
  for (int nt = 0; nt < 4; ++nt){
    float s1 = psum[nt], s2 = psq[nt];
    s1 += __shfl_xor(s1, 16, 64);  s2 += __shfl_xor(s2, 16, 64);
    s1 += __shfl_xor(s1, 32, 64);  s2 += __shfl_xor(s2, 32, 64);
    if (quad == 0){
      atomicAdd(&stats[nt*16 + l15], s1);
      atomicAdd(&stats[64 + nt*16 + l15], s2);
    }
  }

  // dump min/max slab partials (bf16; rounding is monotone so max/min commute with it)
  const size_t slab = (size_t)blockIdx.y * OUTN_;
  const int h = h0 + wv;
  #pragma unroll
  for (int mh = 0; mh < 2; ++mh)
    #pragma unroll
    for (int nt = 0; nt < 4; ++nt){
      int o = nt*16 + l15;
      #pragma unroll
      for (int rg = 0; rg < 4; ++rg){
        int w = mh*16 + quad*4 + rg;
        size_t idx = slab + ((size_t)(b*64 + o))*HW_ + h*W_ + w;
        maxp[idx] = __float2bfloat16(mmx[mh][nt][rg]);
        minp[idx] = __float2bfloat16(mmn[mh][nt][rg]);
      }
    }
}

// ---------------- final: reduce slabs, apply BN3+ReLU via monotonicity ----------------

__global__ void bevreduce_kernel(const bf16* __restrict__ minp, const bf16* __restrict__ maxp,
                                 const float* __restrict__ ss, float* __restrict__ out, int nslab){
  int j = blockIdx.x*blockDim.x + threadIdx.x;
  if (j >= OUTN_) return;
  int o = (j >> 12) & 63;
  float mx = -FLT_MAX, mn = FLT_MAX;
  for (int s = 0; s < nslab; ++s){
    mx = fmaxf(mx, __bfloat162float(maxp[(size_t)s*OUTN_ + j]));
    mn = fminf(mn, __bfloat162float(minp[(size_t)s*OUTN_ + j]));
  }
  float a = ss[o], sh = ss[64 + o];
  float v = (a >= 0.f) ? mx : mn;
  out[j] = fmaxf(fmaf(a, v, sh), 0.f);
}

// ---------------- BN finalize ----------------

__global__ void finalize_kernel(const float* __restrict__ stats, const float* __restrict__ gamma,
                                const float* __restrict__ beta, float* __restrict__ ss, int C){
  int c = threadIdx.x;
  if (c >= C) return;
  const float invCnt = 1.0f / (float)((size_t)B_*DHW_);
  float mean = stats[c] * invCnt;
  float var  = stats[C + c] * invCnt - mean*mean;
  float a = gamma[c] * rsqrtf(var + EPSV);
  ss[c]     = a;
  ss[C + c] = beta[c] - mean*a;
}

// ---------------- launch ----------------

extern "C" void kernel_launch(void* const* d_in, const int* in_sizes, int n_in,
                              void* d_out, int out_size, void* d_ws, size_t ws_size,
                              hipStream_t stream){
  const float* pc  = (const float*)d_in[0];
  const float* w1  = (const float*)d_in[1];
  const float* b1  = (const float*)d_in[2];
  const float* g1  = (const float*)d_in[3];
  const float* be1 = (const float*)d_in[4];
  const float* w2  = (const float*)d_in[5];
  const float* b2  = (const float*)d_in[6];
  const float* g2  = (const float*)d_in[7];
  const float* be2 = (const float*)d_in[8];
  const float* w3  = (const float*)d_in[9];
  const float* b3  = (const float*)d_in[10];
  const float* g3  = (const float*)d_in[11];
  const float* be3 = (const float*)d_in[12];
  const int N = in_sizes[0] / 6;  // (B=2, 3, N)
  float* out = (float*)d_out;

  char* wsb = (char*)d_ws;
  size_t off = 0;
  auto alloc = [&](size_t bytes)->char*{
    off = (off + 255) & ~(size_t)255;
    char* p = wsb + off; off += bytes; return p;
  };
  float* g0   = (float*)alloc((size_t)B_*DHW_*4);   // 4 MB
  float* wr1  = (float*)alloc(864*4);
  float* wr2  = (float*)alloc(55296*4);
  bf16*  wr3b = (bf16*) alloc(110592*2);            // [tap][o][i] bf16
  float* mins = (float*)alloc(8*4);
  float* st   = (float*)alloc(3*128*4);
  float* ss   = (float*)alloc(3*128*4);

  constexpr int DCHUNK = 16;
  constexpr int NSLAB  = D_ / DCHUNK;          // 8
  const size_t SX2B  = (size_t)B_*64*DHW_*2;   // 128 MiB bf16
  const size_t SX2C  = (size_t)B_*64*DHW_;     // 64 MiB fp8
  const size_t SMM   = (size_t)NSLAB*OUTN_*2;  // 8 MiB per min/max array
  const size_t prefix = (off + 255) & ~(size_t)255;
  const size_t needB = prefix + 2*SMM + SX2B + 3*256;

  bf16* maxp = (bf16*)alloc(SMM);
  bf16* minp = (bf16*)alloc(SMM);

  // common prologue
  zero_kernel<<<(B_*DHW_ + 255)/256, 256, 0, stream>>>(g0, B_*DHW_);
  zero_kernel<<<2, 256, 0, stream>>>(st, 3*128);
  min_kernel<<<B_*3, 256, 0, stream>>>(pc, mins, N);
  scatter_kernel<<<(B_*N + 255)/256, 256, 0, stream>>>(pc, mins, g0, N);
  reorder_kernel<<<(864 + 255)/256, 256, 0, stream>>>(w1, wr1, 1, 32);
  reorder_kernel<<<(55296 + 255)/256, 256, 0, stream>>>(w2, wr2, 32, 64);
  reorder3b_kernel<<<(110592 + 255)/256, 256, 0, stream>>>(w3, wr3b);

  dim3 cgrid(16, 128, 2);                      // (8h-tiles, d, b) for conv1/fused12
  dim3 mgrid(32, NSLAB, 2);                    // (4h-tiles, d-slabs, b) = 512 blocks

  convstats_kernel<1,32,float><<<cgrid, 256, 0, stream>>>(g0, wr1, b1, st);
  finalize_kernel<<<1, 64, 0, stream>>>(st, g1, be1, ss, 32);

  if (ws_size >= needB){
    bf16* x2 = (bf16*)alloc(SX2B);
    fused12_kernel<bf16><<<cgrid, 256, 0, stream>>>(g0, wr1, b1, ss, wr2, b2, x2, st + 128);
    finalize_kernel<<<1, 64, 0, stream>>>(st + 128, g2, be2, ss + 128, 64);
    conv3mfma_kernel<bf16,DCHUNK><<<mgrid, 256, 0, stream>>>(x2, wr3b, b3, ss + 128, st + 256, minp, maxp);
  } else {
    fp8s* x2 = (fp8s*)alloc(SX2C);
    fused12_kernel<fp8s><<<cgrid, 256, 0, stream>>>(g0, wr1, b1, ss, wr2, b2, x2, st + 128);
    finalize_kernel<<<1, 64, 0, stream>>>(st + 128, g2, be2, ss + 128, 64);
    conv3mfma_kernel<fp8s,DCHUNK><<<mgrid, 256, 0, stream>>>(x2, wr3b, b3, ss + 128, st + 256, minp, maxp);
  }
  finalize_kernel<<<1, 64, 0, stream>>>(st + 256, g3, be3, ss + 256, 64);
  bevreduce_kernel<<<(OUTN_ + 255)/256, 256, 0, stream>>>(minp, maxp, ss + 256, out, NSLAB);
}

// Round 8
// 3211.390 us; speedup vs baseline: 3.9822x; 1.2873x over previous
//
#include <hip/hip_runtime.h>
#include <hip/hip_bf16.h>
#include <float.h>

// LiDAR BEV pipeline (fp32 I/O):
//   voxelize -> conv3d(1->32)+BN+ReLU -> conv3d(32->64)+BN+ReLU -> conv3d(64->64)+BN+ReLU -> max over D
// R7: 4.13ms. conv3mfma was staging-VALU + B-L1-duplication bound. R8:
//  - x2 stored channel-last [b][d][h][w][64] bf16 (raw), BN2+ReLU applied by a cheap
//    in-place pass -> conv3 A-staging is pure global_load_lds (dwordx4) copies.
//  - conv3: d-pair packing (B-fragments in regs reused for 2 d's, traffic /2),
//    A-tile [4][6][34][32] (52KB), conflict-free fragment reads.
//  - fused12 epilogue now does one 16B store per (h) instead of 8 scattered 2B stores.

#define VOXEL 0.0625f
#define D_ 128
#define H_ 128
#define W_ 32
#define HW_ (H_*W_)      // 4096
#define DHW_ (D_*H_*W_)  // 524288
#define B_ 2
#define EPSV 1e-5f
#define OUTN_ (B_*64*HW_) // 524288

typedef __hip_bfloat16 bf16;
typedef __attribute__((ext_vector_type(8))) short short8;   // 8 bf16
typedef __attribute__((ext_vector_type(4))) float f32x4;

__device__ inline void gl_lds16(const void* g, void* l){
  // async global->LDS, 16B per lane; LDS dest = base + lane*16 (wave-uniform base)
  __builtin_amdgcn_global_load_lds(
      (const __attribute__((address_space(1))) unsigned int*)g,
      (__attribute__((address_space(3))) unsigned int*)l, 16, 0, 0);
}

// ---------------- init ----------------

__global__ void zero_kernel(float* __restrict__ p, int n){
  int i = blockIdx.x*blockDim.x + threadIdx.x;
  if (i < n) p[i] = 0.f;
}

// ---------------- voxelize ----------------

__global__ void min_kernel(const float* __restrict__ pc, float* __restrict__ mins, int N){
  const float* base = pc + (size_t)blockIdx.x * N;
  float m = FLT_MAX;
  for (int j = threadIdx.x; j < N; j += blockDim.x){
    float v = base[j];
    if (v != v) v = 0.f;          // NaN -> 0, matching reference
    m = fminf(m, v);
  }
  for (int off = 32; off > 0; off >>= 1)
    m = fminf(m, __shfl_xor(m, off, 64));
  __shared__ float red[4];
  int wave = threadIdx.x >> 6;
  if ((threadIdx.x & 63) == 0) red[wave] = m;
  __syncthreads();
  if (threadIdx.x == 0){
    float r = red[0];
    for (int k = 1; k < (int)(blockDim.x >> 6); ++k) r = fminf(r, red[k]);
    mins[blockIdx.x] = r;
  }
}

__global__ void scatter_kernel(const float* __restrict__ pc, const float* __restrict__ mins,
                               float* __restrict__ grid, int N){
  int idx = blockIdx.x*blockDim.x + threadIdx.x;
  if (idx >= B_*N) return;
  int b = idx / N, n = idx - b*N;
  float x = pc[((size_t)b*3 + 0)*N + n];
  float y = pc[((size_t)b*3 + 1)*N + n];
  float z = pc[((size_t)b*3 + 2)*N + n];
  if (x != x) x = 0.f;
  if (y != y) y = 0.f;
  if (z != z) z = 0.f;
  int ix = (int)floorf((x - mins[b*3+0]) / VOXEL);
  int iy = (int)floorf((y - mins[b*3+1]) / VOXEL);
  int iz = (int)floorf((z - mins[b*3+2]) / VOXEL);
  ix = min(max(ix, 0), D_-1);
  iy = min(max(iy, 0), H_-1);
  iz = min(max(iz, 0), W_-1);
  grid[(size_t)b*DHW_ + (size_t)ix*HW_ + iy*W_ + iz] = 1.0f;
}

// ---------------- weight reorders ----------------

__global__ void reorder_kernel(const float* __restrict__ w, float* __restrict__ wr, int CIN, int COUT){
  int idx = blockIdx.x*blockDim.x + threadIdx.x;
  int total = COUT*CIN*27;
  if (idx >= total) return;
  int o = idx / (CIN*27);
  int rem = idx - o*(CIN*27);
  int i = rem / 27;
  int k = rem - i*27;
  wr[(i*27 + k)*COUT + o] = w[idx];
}

// w3 (64,64,3,3,3) fp32 -> [tap][o][i] bf16
__global__ void reorder3b_kernel(const float* __restrict__ w, bf16* __restrict__ wb){
  int idx = blockIdx.x*blockDim.x + threadIdx.x;
  if (idx >= 64*64*27) return;
  int o = idx / (64*27);
  int rem = idx - o*(64*27);
  int i = rem / 27;
  int tap = rem - i*27;
  wb[((size_t)tap*64 + o)*64 + i] = __float2bfloat16(w[idx]);
}

// ---------------- fp32 conv inner (conv1/fused12) ----------------

template<int HT, int OPT, int COUT>
__device__ inline void conv_inner(float (*xs)[HT+2][34], float (*wsm)[COUT],
                                  int w, int og, float (*acc)[OPT]){
  #pragma unroll
  for (int kd = 0; kd < 3; ++kd){
    float xr[HT+2][3];
    #pragma unroll
    for (int r = 0; r < HT+2; ++r)
      #pragma unroll
      for (int c = 0; c < 3; ++c)
        xr[r][c] = xs[kd][r][w + c];
    #pragma unroll
    for (int kh = 0; kh < 3; ++kh)
      #pragma unroll
      for (int kw = 0; kw < 3; ++kw){
        const float* wp = &wsm[kd*9 + kh*3 + kw][og*OPT];
        float wv[OPT];
        #pragma unroll
        for (int oo = 0; oo < OPT; ++oo) wv[oo] = wp[oo];
        #pragma unroll
        for (int h = 0; h < HT; ++h){
          float xv = xr[h + kh][kw];
          #pragma unroll
          for (int oo = 0; oo < OPT; ++oo)
            acc[h][oo] = fmaf(xv, wv[oo], acc[h][oo]);
        }
      }
  }
}

// ---------------- conv1 BN stats (CIN=1, cheap) ----------------

__global__ __launch_bounds__(256)
void convstats_kernel(const float* __restrict__ X, const float* __restrict__ WR,
                      const float* __restrict__ bias, float* __restrict__ stats){
  const int tid = threadIdx.x;
  const int w   = tid & 31;
  const int og  = tid >> 5;
  const int h0  = blockIdx.x * 8;
  const int d   = blockIdx.y;
  const int b   = blockIdx.z;

  __shared__ float xs[3][10][34];
  __shared__ float wsm[27][32];

  float acc[8][4];
  #pragma unroll
  for (int h = 0; h < 8; ++h)
    #pragma unroll
    for (int oo = 0; oo < 4; ++oo) acc[h][oo] = 0.f;

  for (int e = tid; e < 27*32; e += 256)
    ((float*)wsm)[e] = WR[e];
  for (int e = tid; e < 960; e += 256){
    int ds = e / 320; int rem = e - ds*320; int r = rem >> 5; int ww = rem & 31;
    int dd = d + ds - 1, hh = h0 + r - 1;
    float v = 0.f;
    if (dd >= 0 && dd < D_ && hh >= 0 && hh < H_)
      v = X[((size_t)b*D_ + dd)*HW_ + hh*W_ + ww];
    xs[ds][r][ww + 1] = v;
  }
  if (tid < 30){ int ds = tid/10, r = tid - ds*10; xs[ds][r][0] = 0.f; xs[ds][r][33] = 0.f; }
  __syncthreads();
  conv_inner<8, 4, 32>(xs, wsm, w, og, acc);

  #pragma unroll
  for (int oo = 0; oo < 4; ++oo){
    int o = og*4 + oo;
    float bo = bias[o];
    float s1 = 0.f, s2 = 0.f;
    #pragma unroll
    for (int h = 0; h < 8; ++h){
      float y = acc[h][oo] + bo;
      s1 += y;
      s2 = fmaf(y, y, s2);
    }
    for (int m = 16; m > 0; m >>= 1){
      s1 += __shfl_xor(s1, m, 32);
      s2 += __shfl_xor(s2, m, 32);
    }
    if (w == 0){
      atomicAdd(&stats[o], s1);
      atomicAdd(&stats[32 + o], s2);
    }
  }
}

// ---------------- fused conv1+BN1+ReLU + conv2 -> x2 channel-last RAW + BN2 stats ----------------

__global__ __launch_bounds__(256)
void fused12_kernel(const float* __restrict__ G0, const float* __restrict__ WR1,
                    const float* __restrict__ B1, const float* __restrict__ SS1,
                    const float* __restrict__ WR2, const float* __restrict__ B2,
                    bf16* __restrict__ X2, float* __restrict__ stats){
  const int tid = threadIdx.x;
  const int w   = tid & 31;
  const int og  = tid >> 5;
  const int h0  = blockIdx.x * 8;
  const int d   = blockIdx.y;
  const int b   = blockIdx.z;

  __shared__ float gs[5][12][34];
  __shared__ float w1s[32][27];
  __shared__ float xs[3][10][34];
  __shared__ float wsm[27][64];

  for (int e = tid; e < 5*12*34; e += 256){
    int ds = e / 408; int rem = e - ds*408; int r = rem / 34; int c = rem - r*34;
    int dd = d - 2 + ds, hh = h0 - 2 + r, ww = c - 1;
    float v = 0.f;
    if (c >= 1 && c <= 32 && dd >= 0 && dd < D_ && hh >= 0 && hh < H_)
      v = G0[((size_t)b*D_ + dd)*HW_ + hh*W_ + ww];
    gs[ds][r][c] = v;
  }
  for (int e = tid; e < 864; e += 256){
    int i = e/27, k = e - 27*i;
    w1s[i][k] = WR1[k*32 + i];
  }

  float acc[8][8];
  #pragma unroll
  for (int h = 0; h < 8; ++h)
    #pragma unroll
    for (int oo = 0; oo < 8; ++oo) acc[h][oo] = 0.f;

  for (int i = 0; i < 32; ++i){
    __syncthreads();
    float a1 = SS1[i];
    float f1 = fmaf(a1, B1[i], SS1[32 + i]);
    for (int e = tid; e < 1020; e += 256){
      int ds = e / 340; int rem = e - ds*340; int r = rem / 34; int c = rem - r*34;
      float v = 0.f;
      int dd = d - 1 + ds, hh = h0 - 1 + r;
      if (c >= 1 && c <= 32 && dd >= 0 && dd < D_ && hh >= 0 && hh < H_){
        float s = 0.f;
        #pragma unroll
        for (int kd = 0; kd < 3; ++kd)
          #pragma unroll
          for (int kh = 0; kh < 3; ++kh)
            #pragma unroll
            for (int kw = 0; kw < 3; ++kw)
              s = fmaf(gs[ds+kd][r+kh][c-1+kw], w1s[i][kd*9+kh*3+kw], s);
        v = fmaxf(fmaf(a1, s, f1), 0.f);
      }
      xs[ds][r][c] = v;
    }
    for (int e = tid; e < 27*64; e += 256)
      ((float*)wsm)[e] = WR2[i*27*64 + e];
    __syncthreads();
    conv_inner<8, 8, 64>(xs, wsm, w, og, acc);
  }

  float bo[8], psum[8], psq[8];
  #pragma unroll
  for (int oo = 0; oo < 8; ++oo){ bo[oo] = B2[og*8 + oo]; psum[oo] = 0.f; psq[oo] = 0.f; }
  #pragma unroll
  for (int h = 0; h < 8; ++h){
    bf16 row[8];
    #pragma unroll
    for (int oo = 0; oo < 8; ++oo){
      float y = acc[h][oo] + bo[oo];
      row[oo] = __float2bfloat16(y);
      psum[oo] += y;
      psq[oo]  = fmaf(y, y, psq[oo]);
    }
    // channel-last: one 16B store for 8 consecutive o
    *(short8*)&X2[((((size_t)b*D_ + d)*H_ + (h0 + h))*W_ + w)*64 + og*8] = *(short8*)row;
  }
  #pragma unroll
  for (int oo = 0; oo < 8; ++oo){
    float s1 = psum[oo], s2 = psq[oo];
    for (int m = 16; m > 0; m >>= 1){
      s1 += __shfl_xor(s1, m, 32);
      s2 += __shfl_xor(s2, m, 32);
    }
    if (w == 0){
      atomicAdd(&stats[og*8 + oo], s1);
      atomicAdd(&stats[64 + og*8 + oo], s2);
    }
  }
}

// ---------------- in-place BN2+ReLU on channel-last x2 ----------------

__global__ void bnact_kernel(bf16* __restrict__ x, const float* __restrict__ ss){
  size_t i8 = (size_t)blockIdx.x*blockDim.x + threadIdx.x;
  if (i8 >= (size_t)B_*DHW_*8) return;   // 64ch/8 per thread
  int ob = ((int)(i8 & 7)) * 8;
  bf16* p = x + i8*8;
  short8 v = *(short8*)p;
  bf16* pv = (bf16*)&v;
  #pragma unroll
  for (int j = 0; j < 8; ++j){
    int o = ob + j;
    float f = fmaxf(fmaf(ss[o], __bfloat162float(pv[j]), ss[64 + o]), 0.f);
    pv[j] = __float2bfloat16(f);
  }
  *(short8*)p = v;
}

// ---------------- conv3 MFMA: d-paired, async-staged, + BN3 stats + min/max over d ----------------
// Block: 4 h-rows x 32 w x 64 o. A-tile [4 d-slices][6 r][34 w'][32 ch] bf16 (52KB),
// staged via global_load_lds from channel-last post-act x2. B-frags (regs) reused
// across the d-pair. y3 min/max per (w,o) kept in VGPRs, dumped per 16-d slab.

template<int DCHUNK>
__global__ __launch_bounds__(256, 2)
void conv3mfma_kernel(const bf16* __restrict__ X, const bf16* __restrict__ WB,
                      const float* __restrict__ bias, float* __restrict__ stats,
                      bf16* __restrict__ minp, bf16* __restrict__ maxp){
  const int tid  = threadIdx.x;
  const int lane = tid & 63;
  const int wv   = tid >> 6;        // wave id = h-row 0..3
  const int l15  = lane & 15;
  const int quad = lane >> 4;       // 0..3
  const int h0   = blockIdx.x * 4;
  const int d0   = blockIdx.y * DCHUNK;
  const int b    = blockIdx.z;

  __shared__ __align__(16) bf16 at[4][6][34][32];   // 52,224 B

  // zero the w-halo columns (w'=0,33) once; staging never writes them
  for (int e = tid; e < 4*6*2*32; e += 256){
    int ch = e & 31; int side = (e >> 5) & 1; int r = (e >> 6) % 6; int sl = (e >> 6) / 6;
    at[sl][r][side ? 33 : 0][ch] = __float2bfloat16(0.f);
  }

  f32x4 acc[2][2][4];               // [dp][mh][nt]
  float mmx[2][4][4], mmn[2][4][4]; // [mh][nt][rg]
  float brg[4];
  #pragma unroll
  for (int nt = 0; nt < 4; ++nt) brg[nt] = bias[nt*16 + l15];
  #pragma unroll
  for (int mh = 0; mh < 2; ++mh)
    #pragma unroll
    for (int nt = 0; nt < 4; ++nt)
      #pragma unroll
      for (int rg = 0; rg < 4; ++rg){ mmx[mh][nt][rg] = -FLT_MAX; mmn[mh][nt][rg] = FLT_MAX; }
  float psum[4] = {0.f,0.f,0.f,0.f}, psq[4] = {0.f,0.f,0.f,0.f};

  const int wlane = lane >> 2;      // 0..15 : w within 16-group
  const int cq    = lane & 3;       // 16B channel chunk

  for (int p = 0; p < DCHUNK/2; ++p){
    const int d = d0 + 2*p;
    #pragma unroll
    for (int dp = 0; dp < 2; ++dp)
      #pragma unroll
      for (int mh = 0; mh < 2; ++mh)
        #pragma unroll
        for (int nt = 0; nt < 4; ++nt)
          acc[dp][mh][nt] = (f32x4){0.f, 0.f, 0.f, 0.f};

    for (int ic = 0; ic < 2; ++ic){
      __syncthreads();
      // stage 4 d-slices x 6 rows (each row: 32w x 32ch = 2KB = 2 wave-insts)
      for (int j = wv; j < 24; j += 4){
        int sl = j / 6, r = j - sl*6;
        int dd = d - 1 + sl, hh = h0 - 1 + r;
        if (dd >= 0 && dd < D_ && hh >= 0 && hh < H_){
          const bf16* rowp = X + (((size_t)b*D_ + dd)*H_ + hh)*W_*64 + ic*32 + cq*8;
          #pragma unroll
          for (int half = 0; half < 2; ++half)
            gl_lds16(rowp + (size_t)(wlane + half*16)*64, &at[sl][r][1 + half*16][0]);
        } else {
          short8 z = {0,0,0,0,0,0,0,0};
          #pragma unroll
          for (int half = 0; half < 2; ++half)
            *(short8*)(&at[sl][r][1 + half*16][0] + lane*8) = z;
        }
      }
      __syncthreads();

      // 27 taps; B-frags loaded once per tap, reused for both d's of the pair
      #pragma unroll
      for (int kd = 0; kd < 3; ++kd)
        #pragma unroll
        for (int kh = 0; kh < 3; ++kh)
          #pragma unroll
          for (int kw = 0; kw < 3; ++kw){
            const bf16* wb = WB + (size_t)((kd*3 + kh)*3 + kw)*64*64 + ic*32 + quad*8;
            short8 bfr[4];
            #pragma unroll
            for (int nt = 0; nt < 4; ++nt)
              bfr[nt] = *(const short8*)(wb + (nt*16 + l15)*64);
            #pragma unroll
            for (int dp = 0; dp < 2; ++dp){
              short8 af[2];
              #pragma unroll
              for (int mh = 0; mh < 2; ++mh)
                af[mh] = *(const short8*)&at[dp + kd][wv + kh][mh*16 + l15 + kw][quad*8];
              #pragma unroll
              for (int mh = 0; mh < 2; ++mh)
                #pragma unroll
                for (int nt = 0; nt < 4; ++nt)
                  acc[dp][mh][nt] = __builtin_amdgcn_mfma_f32_16x16x32_bf16(af[mh], bfr[nt], acc[dp][mh][nt], 0, 0, 0);
            }
          }
    }

    // pair epilogue
    #pragma unroll
    for (int dp = 0; dp < 2; ++dp)
      #pragma unroll
      for (int mh = 0; mh < 2; ++mh)
        #pragma unroll
        for (int nt = 0; nt < 4; ++nt)
          #pragma unroll
          for (int rg = 0; rg < 4; ++rg){
            float y = acc[dp][mh][nt][rg] + brg[nt];
            psum[nt] += y;
            psq[nt]  = fmaf(y, y, psq[nt]);
            mmx[mh][nt][rg] = fmaxf(mmx[mh][nt][rg], y);
            mmn[mh][nt][rg] = fminf(mmn[mh][nt][rg], y);
          }
  }

  // BN3 stats: lanes {l15, +16, +32, +48} share o = nt*16 + l15
  #pragma unroll
  for (int nt = 0; nt < 4; ++nt){
    float s1 = psum[nt], s2 = psq[nt];
    s1 += __shfl_xor(s1, 16, 64);  s2 += __shfl_xor(s2, 16, 64);
    s1 += __shfl_xor(s1, 32, 64);  s2 += __shfl_xor(s2, 32, 64);
    if (quad == 0){
      atomicAdd(&stats[nt*16 + l15], s1);
      atomicAdd(&stats[64 + nt*16 + l15], s2);
    }
  }

  // dump min/max slab partials
  const size_t slab = (size_t)blockIdx.y * OUTN_;
  const int h = h0 + wv;
  #pragma unroll
  for (int mh = 0; mh < 2; ++mh)
    #pragma unroll
    for (int nt = 0; nt < 4; ++nt){
      int o = nt*16 + l15;
      #pragma unroll
      for (int rg = 0; rg < 4; ++rg){
        int w = mh*16 + quad*4 + rg;
        size_t idx = slab + ((size_t)(b*64 + o))*HW_ + h*W_ + w;
        maxp[idx] = __float2bfloat16(mmx[mh][nt][rg]);
        minp[idx] = __float2bfloat16(mmn[mh][nt][rg]);
      }
    }
}

// ---------------- final: reduce slabs, apply BN3+ReLU via monotonicity ----------------

__global__ void bevreduce_kernel(const bf16* __restrict__ minp, const bf16* __restrict__ maxp,
                                 const float* __restrict__ ss, float* __restrict__ out, int nslab){
  int j = blockIdx.x*blockDim.x + threadIdx.x;
  if (j >= OUTN_) return;
  int o = (j >> 12) & 63;
  float mx = -FLT_MAX, mn = FLT_MAX;
  for (int s = 0; s < nslab; ++s){
    mx = fmaxf(mx, __bfloat162float(maxp[(size_t)s*OUTN_ + j]));
    mn = fminf(mn, __bfloat162float(minp[(size_t)s*OUTN_ + j]));
  }
  float a = ss[o], sh = ss[64 + o];
  float v = (a >= 0.f) ? mx : mn;   // relu(a*z+s) monotone in z, direction sign(a)
  out[j] = fmaxf(fmaf(a, v, sh), 0.f);
}

// ---------------- BN finalize ----------------

__global__ void finalize_kernel(const float* __restrict__ stats, const float* __restrict__ gamma,
                                const float* __restrict__ beta, float* __restrict__ ss, int C){
  int c = threadIdx.x;
  if (c >= C) return;
  const float invCnt = 1.0f / (float)((size_t)B_*DHW_);
  float mean = stats[c] * invCnt;
  float var  = stats[C + c] * invCnt - mean*mean;
  float a = gamma[c] * rsqrtf(var + EPSV);
  ss[c]     = a;
  ss[C + c] = beta[c] - mean*a;
}

// ---------------- launch ----------------

extern "C" void kernel_launch(void* const* d_in, const int* in_sizes, int n_in,
                              void* d_out, int out_size, void* d_ws, size_t ws_size,
                              hipStream_t stream){
  const float* pc  = (const float*)d_in[0];
  const float* w1  = (const float*)d_in[1];
  const float* b1  = (const float*)d_in[2];
  const float* g1  = (const float*)d_in[3];
  const float* be1 = (const float*)d_in[4];
  const float* w2  = (const float*)d_in[5];
  const float* b2  = (const float*)d_in[6];
  const float* g2  = (const float*)d_in[7];
  const float* be2 = (const float*)d_in[8];
  const float* w3  = (const float*)d_in[9];
  const float* b3  = (const float*)d_in[10];
  const float* g3  = (const float*)d_in[11];
  const float* be3 = (const float*)d_in[12];
  const int N = in_sizes[0] / 6;  // (B=2, 3, N)
  float* out = (float*)d_out;

  char* wsb = (char*)d_ws;
  size_t off = 0;
  auto alloc = [&](size_t bytes)->char*{
    off = (off + 255) & ~(size_t)255;
    char* p = wsb + off; off += bytes; return p;
  };
  float* g0   = (float*)alloc((size_t)B_*DHW_*4);   // 4 MB
  float* wr1  = (float*)alloc(864*4);
  float* wr2  = (float*)alloc(55296*4);
  bf16*  wr3b = (bf16*) alloc(110592*2);            // [tap][o][i] bf16
  float* mins = (float*)alloc(8*4);
  float* st   = (float*)alloc(3*128*4);             // raw-y sum/sumsq per layer (l1 uses 64)
  float* ss   = (float*)alloc(3*128*4);             // scale/shift per layer

  constexpr int DCHUNK = 16;
  constexpr int NSLAB  = D_ / DCHUNK;               // 8
  const size_t SX2  = (size_t)B_*DHW_*64*2;         // 128 MiB channel-last bf16
  const size_t SMM  = (size_t)NSLAB*OUTN_*2;        // 8 MiB per min/max array

  bf16* maxp = (bf16*)alloc(SMM);
  bf16* minp = (bf16*)alloc(SMM);
  bf16* x2   = (bf16*)alloc(SX2);                   // total ~155.6MB, == R7 watermark (fits)

  // prologue
  zero_kernel<<<(B_*DHW_ + 255)/256, 256, 0, stream>>>(g0, B_*DHW_);
  zero_kernel<<<2, 256, 0, stream>>>(st, 3*128);
  min_kernel<<<B_*3, 256, 0, stream>>>(pc, mins, N);
  scatter_kernel<<<(B_*N + 255)/256, 256, 0, stream>>>(pc, mins, g0, N);
  reorder_kernel<<<(864 + 255)/256, 256, 0, stream>>>(w1, wr1, 1, 32);
  reorder_kernel<<<(55296 + 255)/256, 256, 0, stream>>>(w2, wr2, 32, 64);
  reorder3b_kernel<<<(110592 + 255)/256, 256, 0, stream>>>(w3, wr3b);

  dim3 cgrid(16, 128, 2);                           // (8h-tiles, d, b)
  dim3 mgrid(32, NSLAB, 2);                         // (4h-tiles, 16d-slabs, b) = 512

  convstats_kernel<<<cgrid, 256, 0, stream>>>(g0, wr1, b1, st);
  finalize_kernel<<<1, 64, 0, stream>>>(st, g1, be1, ss, 32);

  fused12_kernel<<<cgrid, 256, 0, stream>>>(g0, wr1, b1, ss, wr2, b2, x2, st + 128);
  finalize_kernel<<<1, 64, 0, stream>>>(st + 128, g2, be2, ss + 128, 64);

  bnact_kernel<<<(int)(((size_t)B_*DHW_*8 + 255)/256), 256, 0, stream>>>(x2, ss + 128);

  conv3mfma_kernel<DCHUNK><<<mgrid, 256, 0, stream>>>(x2, wr3b, b3, st + 256, minp, maxp);
  finalize_kernel<<<1, 64, 0, stream>>>(st + 256, g3, be3, ss + 256, 64);
  bevreduce_kernel<<<(OUTN_ + 255)/256, 256, 0, stream>>>(minp, maxp, ss + 256, out, NSLAB);
}

// Round 9
// 2241.751 us; speedup vs baseline: 5.7047x; 1.4325x over previous
//
#include <hip/hip_runtime.h>
#include <hip/hip_bf16.h>
#include <float.h>

// LiDAR BEV pipeline (fp32 I/O):
//   voxelize -> conv3d(1->32)+BN+ReLU -> conv3d(32->64)+BN+ReLU -> conv3d(64->64)+BN+ReLU -> max over D
// R8: 3.21ms, fused12 (fp32 conv1-recompute + fp32 conv2) is the whale at 1.9ms.
// R9: split it -> conv1act writes post-act x1 channel-last bf16 (64MiB, aliases the
// min/max region; disjoint lifetimes), conv2 becomes MFMA implicit-GEMM with swapped
// operands (weights=A so each lane owns 4 consecutive o -> coalesced 8B stores).
// Runtime gate on ws_size (>=~206MB) with exact-R8 fallback.

#define VOXEL 0.0625f
#define D_ 128
#define H_ 128
#define W_ 32
#define HW_ (H_*W_)      // 4096
#define DHW_ (D_*H_*W_)  // 524288
#define B_ 2
#define EPSV 1e-5f
#define OUTN_ (B_*64*HW_) // 524288

typedef __hip_bfloat16 bf16;
typedef __attribute__((ext_vector_type(8))) short short8;   // 8 bf16
typedef __attribute__((ext_vector_type(4))) short short4v;  // 4 bf16
typedef __attribute__((ext_vector_type(4))) float f32x4;

__device__ inline void gl_lds16(const void* g, void* l){
  // async global->LDS, 16B per lane; LDS dest = base + lane*16 (wave-uniform base)
  __builtin_amdgcn_global_load_lds(
      (const __attribute__((address_space(1))) unsigned int*)g,
      (__attribute__((address_space(3))) unsigned int*)l, 16, 0, 0);
}

// ---------------- init ----------------

__global__ void zero_kernel(float* __restrict__ p, int n){
  int i = blockIdx.x*blockDim.x + threadIdx.x;
  if (i < n) p[i] = 0.f;
}

// ---------------- voxelize ----------------

__global__ void min_kernel(const float* __restrict__ pc, float* __restrict__ mins, int N){
  const float* base = pc + (size_t)blockIdx.x * N;
  float m = FLT_MAX;
  for (int j = threadIdx.x; j < N; j += blockDim.x){
    float v = base[j];
    if (v != v) v = 0.f;          // NaN -> 0, matching reference
    m = fminf(m, v);
  }
  for (int off = 32; off > 0; off >>= 1)
    m = fminf(m, __shfl_xor(m, off, 64));
  __shared__ float red[4];
  int wave = threadIdx.x >> 6;
  if ((threadIdx.x & 63) == 0) red[wave] = m;
  __syncthreads();
  if (threadIdx.x == 0){
    float r = red[0];
    for (int k = 1; k < (int)(blockDim.x >> 6); ++k) r = fminf(r, red[k]);
    mins[blockIdx.x] = r;
  }
}

__global__ void scatter_kernel(const float* __restrict__ pc, const float* __restrict__ mins,
                               float* __restrict__ grid, int N){
  int idx = blockIdx.x*blockDim.x + threadIdx.x;
  if (idx >= B_*N) return;
  int b = idx / N, n = idx - b*N;
  float x = pc[((size_t)b*3 + 0)*N + n];
  float y = pc[((size_t)b*3 + 1)*N + n];
  float z = pc[((size_t)b*3 + 2)*N + n];
  if (x != x) x = 0.f;
  if (y != y) y = 0.f;
  if (z != z) z = 0.f;
  int ix = (int)floorf((x - mins[b*3+0]) / VOXEL);
  int iy = (int)floorf((y - mins[b*3+1]) / VOXEL);
  int iz = (int)floorf((z - mins[b*3+2]) / VOXEL);
  ix = min(max(ix, 0), D_-1);
  iy = min(max(iy, 0), H_-1);
  iz = min(max(iz, 0), W_-1);
  grid[(size_t)b*DHW_ + (size_t)ix*HW_ + iy*W_ + iz] = 1.0f;
}

// ---------------- weight reorders ----------------

__global__ void reorder_kernel(const float* __restrict__ w, float* __restrict__ wr, int CIN, int COUT){
  int idx = blockIdx.x*blockDim.x + threadIdx.x;
  int total = COUT*CIN*27;
  if (idx >= total) return;
  int o = idx / (CIN*27);
  int rem = idx - o*(CIN*27);
  int i = rem / 27;
  int k = rem - i*27;
  wr[(i*27 + k)*COUT + o] = w[idx];
}

// w3 (64,64,3,3,3) fp32 -> [tap][o][64 i] bf16
__global__ void reorder3b_kernel(const float* __restrict__ w, bf16* __restrict__ wb){
  int idx = blockIdx.x*blockDim.x + threadIdx.x;
  if (idx >= 64*64*27) return;
  int o = idx / (64*27);
  int rem = idx - o*(64*27);
  int i = rem / 27;
  int tap = rem - i*27;
  wb[((size_t)tap*64 + o)*64 + i] = __float2bfloat16(w[idx]);
}

// w2 (64,32,3,3,3) fp32 -> [tap][o][32 i] bf16
__global__ void reorder2b_kernel(const float* __restrict__ w, bf16* __restrict__ wb){
  int idx = blockIdx.x*blockDim.x + threadIdx.x;
  if (idx >= 64*32*27) return;
  int o = idx / (32*27);
  int rem = idx - o*(32*27);
  int i = rem / 27;
  int tap = rem - i*27;
  wb[((size_t)tap*64 + o)*32 + i] = __float2bfloat16(w[idx]);
}

// ---------------- fp32 conv inner (conv1-class kernels) ----------------

template<int HT, int OPT, int COUT>
__device__ inline void conv_inner(float (*xs)[HT+2][34], float (*wsm)[COUT],
                                  int w, int og, float (*acc)[OPT]){
  #pragma unroll
  for (int kd = 0; kd < 3; ++kd){
    float xr[HT+2][3];
    #pragma unroll
    for (int r = 0; r < HT+2; ++r)
      #pragma unroll
      for (int c = 0; c < 3; ++c)
        xr[r][c] = xs[kd][r][w + c];
    #pragma unroll
    for (int kh = 0; kh < 3; ++kh)
      #pragma unroll
      for (int kw = 0; kw < 3; ++kw){
        const float* wp = &wsm[kd*9 + kh*3 + kw][og*OPT];
        float wv[OPT];
        #pragma unroll
        for (int oo = 0; oo < OPT; ++oo) wv[oo] = wp[oo];
        #pragma unroll
        for (int h = 0; h < HT; ++h){
          float xv = xr[h + kh][kw];
          #pragma unroll
          for (int oo = 0; oo < OPT; ++oo)
            acc[h][oo] = fmaf(xv, wv[oo], acc[h][oo]);
        }
      }
  }
}

// ---------------- conv1 BN stats (CIN=1, cheap) ----------------

__global__ __launch_bounds__(256)
void convstats_kernel(const float* __restrict__ X, const float* __restrict__ WR,
                      const float* __restrict__ bias, float* __restrict__ stats){
  const int tid = threadIdx.x;
  const int w   = tid & 31;
  const int og  = tid >> 5;
  const int h0  = blockIdx.x * 8;
  const int d   = blockIdx.y;
  const int b   = blockIdx.z;

  __shared__ float xs[3][10][34];
  __shared__ float wsm[27][32];

  float acc[8][4];
  #pragma unroll
  for (int h = 0; h < 8; ++h)
    #pragma unroll
    for (int oo = 0; oo < 4; ++oo) acc[h][oo] = 0.f;

  for (int e = tid; e < 27*32; e += 256)
    ((float*)wsm)[e] = WR[e];
  for (int e = tid; e < 960; e += 256){
    int ds = e / 320; int rem = e - ds*320; int r = rem >> 5; int ww = rem & 31;
    int dd = d + ds - 1, hh = h0 + r - 1;
    float v = 0.f;
    if (dd >= 0 && dd < D_ && hh >= 0 && hh < H_)
      v = X[((size_t)b*D_ + dd)*HW_ + hh*W_ + ww];
    xs[ds][r][ww + 1] = v;
  }
  if (tid < 30){ int ds = tid/10, r = tid - ds*10; xs[ds][r][0] = 0.f; xs[ds][r][33] = 0.f; }
  __syncthreads();
  conv_inner<8, 4, 32>(xs, wsm, w, og, acc);

  #pragma unroll
  for (int oo = 0; oo < 4; ++oo){
    int o = og*4 + oo;
    float bo = bias[o];
    float s1 = 0.f, s2 = 0.f;
    #pragma unroll
    for (int h = 0; h < 8; ++h){
      float y = acc[h][oo] + bo;
      s1 += y;
      s2 = fmaf(y, y, s2);
    }
    for (int m = 16; m > 0; m >>= 1){
      s1 += __shfl_xor(s1, m, 32);
      s2 += __shfl_xor(s2, m, 32);
    }
    if (w == 0){
      atomicAdd(&stats[o], s1);
      atomicAdd(&stats[32 + o], s2);
    }
  }
}

// ---------------- conv1 + BN1 + ReLU -> x1 channel-last bf16 [b][d][h][w][32] ----------------

__global__ __launch_bounds__(256)
void conv1act_kernel(const float* __restrict__ X, const float* __restrict__ WR,
                     const float* __restrict__ bias, const float* __restrict__ SS1,
                     bf16* __restrict__ X1){
  const int tid = threadIdx.x;
  const int w   = tid & 31;
  const int og  = tid >> 5;
  const int h0  = blockIdx.x * 8;
  const int d   = blockIdx.y;
  const int b   = blockIdx.z;

  __shared__ float xs[3][10][34];
  __shared__ float wsm[27][32];

  float acc[8][4];
  #pragma unroll
  for (int h = 0; h < 8; ++h)
    #pragma unroll
    for (int oo = 0; oo < 4; ++oo) acc[h][oo] = 0.f;

  for (int e = tid; e < 27*32; e += 256)
    ((float*)wsm)[e] = WR[e];
  for (int e = tid; e < 960; e += 256){
    int ds = e / 320; int rem = e - ds*320; int r = rem >> 5; int ww = rem & 31;
    int dd = d + ds - 1, hh = h0 + r - 1;
    float v = 0.f;
    if (dd >= 0 && dd < D_ && hh >= 0 && hh < H_)
      v = X[((size_t)b*D_ + dd)*HW_ + hh*W_ + ww];
    xs[ds][r][ww + 1] = v;
  }
  if (tid < 30){ int ds = tid/10, r = tid - ds*10; xs[ds][r][0] = 0.f; xs[ds][r][33] = 0.f; }
  __syncthreads();
  conv_inner<8, 4, 32>(xs, wsm, w, og, acc);

  float bo[4], a1[4], f1[4];
  #pragma unroll
  for (int oo = 0; oo < 4; ++oo){
    int o = og*4 + oo;
    bo[oo] = bias[o]; a1[oo] = SS1[o]; f1[oo] = SS1[32 + o];
  }
  #pragma unroll
  for (int h = 0; h < 8; ++h){
    bf16 row[4];
    #pragma unroll
    for (int oo = 0; oo < 4; ++oo){
      float y = acc[h][oo] + bo[oo];
      row[oo] = __float2bfloat16(fmaxf(fmaf(a1[oo], y, f1[oo]), 0.f));
    }
    *(short4v*)&X1[((((size_t)b*D_ + d)*H_ + (h0 + h))*W_ + w)*32 + og*4] = *(short4v*)row;
  }
}

// ---------------- fused12 (fp32 fallback, exact R8 path) ----------------

__global__ __launch_bounds__(256)
void fused12_kernel(const float* __restrict__ G0, const float* __restrict__ WR1,
                    const float* __restrict__ B1, const float* __restrict__ SS1,
                    const float* __restrict__ WR2, const float* __restrict__ B2,
                    bf16* __restrict__ X2, float* __restrict__ stats){
  const int tid = threadIdx.x;
  const int w   = tid & 31;
  const int og  = tid >> 5;
  const int h0  = blockIdx.x * 8;
  const int d   = blockIdx.y;
  const int b   = blockIdx.z;

  __shared__ float gs[5][12][34];
  __shared__ float w1s[32][27];
  __shared__ float xs[3][10][34];
  __shared__ float wsm[27][64];

  for (int e = tid; e < 5*12*34; e += 256){
    int ds = e / 408; int rem = e - ds*408; int r = rem / 34; int c = rem - r*34;
    int dd = d - 2 + ds, hh = h0 - 2 + r, ww = c - 1;
    float v = 0.f;
    if (c >= 1 && c <= 32 && dd >= 0 && dd < D_ && hh >= 0 && hh < H_)
      v = G0[((size_t)b*D_ + dd)*HW_ + hh*W_ + ww];
    gs[ds][r][c] = v;
  }
  for (int e = tid; e < 864; e += 256){
    int i = e/27, k = e - 27*i;
    w1s[i][k] = WR1[k*32 + i];
  }

  float acc[8][8];
  #pragma unroll
  for (int h = 0; h < 8; ++h)
    #pragma unroll
    for (int oo = 0; oo < 8; ++oo) acc[h][oo] = 0.f;

  for (int i = 0; i < 32; ++i){
    __syncthreads();
    float a1 = SS1[i];
    float f1 = fmaf(a1, B1[i], SS1[32 + i]);
    for (int e = tid; e < 1020; e += 256){
      int ds = e / 340; int rem = e - ds*340; int r = rem / 34; int c = rem - r*34;
      float v = 0.f;
      int dd = d - 1 + ds, hh = h0 - 1 + r;
      if (c >= 1 && c <= 32 && dd >= 0 && dd < D_ && hh >= 0 && hh < H_){
        float s = 0.f;
        #pragma unroll
        for (int kd = 0; kd < 3; ++kd)
          #pragma unroll
          for (int kh = 0; kh < 3; ++kh)
            #pragma unroll
            for (int kw = 0; kw < 3; ++kw)
              s = fmaf(gs[ds+kd][r+kh][c-1+kw], w1s[i][kd*9+kh*3+kw], s);
        v = fmaxf(fmaf(a1, s, f1), 0.f);
      }
      xs[ds][r][c] = v;
    }
    for (int e = tid; e < 27*64; e += 256)
      ((float*)wsm)[e] = WR2[i*27*64 + e];
    __syncthreads();
    conv_inner<8, 8, 64>(xs, wsm, w, og, acc);
  }

  float bo[8], psum[8], psq[8];
  #pragma unroll
  for (int oo = 0; oo < 8; ++oo){ bo[oo] = B2[og*8 + oo]; psum[oo] = 0.f; psq[oo] = 0.f; }
  #pragma unroll
  for (int h = 0; h < 8; ++h){
    bf16 row[8];
    #pragma unroll
    for (int oo = 0; oo < 8; ++oo){
      float y = acc[h][oo] + bo[oo];
      row[oo] = __float2bfloat16(y);
      psum[oo] += y;
      psq[oo]  = fmaf(y, y, psq[oo]);
    }
    *(short8*)&X2[((((size_t)b*D_ + d)*H_ + (h0 + h))*W_ + w)*64 + og*8] = *(short8*)row;
  }
  #pragma unroll
  for (int oo = 0; oo < 8; ++oo){
    float s1 = psum[oo], s2 = psq[oo];
    for (int m = 16; m > 0; m >>= 1){
      s1 += __shfl_xor(s1, m, 32);
      s2 += __shfl_xor(s2, m, 32);
    }
    if (w == 0){
      atomicAdd(&stats[og*8 + oo], s1);
      atomicAdd(&stats[64 + og*8 + oo], s2);
    }
  }
}

// ---------------- conv2 MFMA: weights=A (M=64 o), activations=B (N=32 w) ----------------
// Block: 4 h-rows x 32 w x 64 o; d-paired. A-tile [4][6][34][32ch] bf16 (52KB) staged
// async from channel-last post-act x1. C-layout: o = mt*16+quad*4+rg (4 consecutive o
// per rg run -> 8B stores), w = nt*16+l15. Writes raw x2 channel-last + BN2 stats.

template<int DCHUNK>
__global__ __launch_bounds__(256, 2)
void conv2mfma_kernel(const bf16* __restrict__ X1, const bf16* __restrict__ WB,
                      const float* __restrict__ B2, bf16* __restrict__ X2,
                      float* __restrict__ stats){
  const int tid  = threadIdx.x;
  const int lane = tid & 63;
  const int wv   = tid >> 6;        // wave id = h-row
  const int l15  = lane & 15;
  const int quad = lane >> 4;
  const int h0   = blockIdx.x * 4;
  const int d0   = blockIdx.y * DCHUNK;
  const int b    = blockIdx.z;

  __shared__ __align__(16) bf16 at[4][6][34][32];   // 52,224 B

  for (int e = tid; e < 4*6*2*32; e += 256){
    int ch = e & 31; int side = (e >> 5) & 1; int r = (e >> 6) % 6; int sl = (e >> 6) / 6;
    at[sl][r][side ? 33 : 0][ch] = __float2bfloat16(0.f);
  }

  f32x4 acc[2][4][2];               // [dp][mt][nt]
  float br[4][4], psum[4][4], psq[4][4];
  #pragma unroll
  for (int mt = 0; mt < 4; ++mt)
    #pragma unroll
    for (int rg = 0; rg < 4; ++rg){
      br[mt][rg] = B2[mt*16 + quad*4 + rg];
      psum[mt][rg] = 0.f; psq[mt][rg] = 0.f;
    }

  const int wlane = lane >> 2;
  const int cq    = lane & 3;

  for (int p = 0; p < DCHUNK/2; ++p){
    const int d = d0 + 2*p;
    #pragma unroll
    for (int dp = 0; dp < 2; ++dp)
      #pragma unroll
      for (int mt = 0; mt < 4; ++mt)
        #pragma unroll
        for (int nt = 0; nt < 2; ++nt)
          acc[dp][mt][nt] = (f32x4){0.f, 0.f, 0.f, 0.f};

    __syncthreads();
    for (int j = wv; j < 24; j += 4){
      int sl = j / 6, r = j - sl*6;
      int dd = d - 1 + sl, hh = h0 - 1 + r;
      if (dd >= 0 && dd < D_ && hh >= 0 && hh < H_){
        const bf16* rowp = X1 + (((size_t)b*D_ + dd)*H_ + hh)*W_*32 + cq*8;
        #pragma unroll
        for (int half = 0; half < 2; ++half)
          gl_lds16(rowp + (size_t)(wlane + half*16)*32, &at[sl][r][1 + half*16][0]);
      } else {
        short8 z = {0,0,0,0,0,0,0,0};
        #pragma unroll
        for (int half = 0; half < 2; ++half)
          *(short8*)(&at[sl][r][1 + half*16][0] + (size_t)lane*8) = z;
      }
    }
    __syncthreads();

    #pragma unroll
    for (int kd = 0; kd < 3; ++kd)
      #pragma unroll
      for (int kh = 0; kh < 3; ++kh)
        #pragma unroll
        for (int kw = 0; kw < 3; ++kw){
          const bf16* wb = WB + (size_t)((kd*3 + kh)*3 + kw)*64*32 + quad*8;
          short8 afw[4];
          #pragma unroll
          for (int mt = 0; mt < 4; ++mt)
            afw[mt] = *(const short8*)(wb + (mt*16 + l15)*32);
          #pragma unroll
          for (int dp = 0; dp < 2; ++dp){
            short8 bfa[2];
            #pragma unroll
            for (int nt = 0; nt < 2; ++nt)
              bfa[nt] = *(const short8*)&at[dp + kd][wv + kh][nt*16 + l15 + kw][quad*8];
            #pragma unroll
            for (int mt = 0; mt < 4; ++mt)
              #pragma unroll
              for (int nt = 0; nt < 2; ++nt)
                acc[dp][mt][nt] = __builtin_amdgcn_mfma_f32_16x16x32_bf16(afw[mt], bfa[nt], acc[dp][mt][nt], 0, 0, 0);
          }
        }

    // pair epilogue: bias, stats, coalesced 8B stores (4 consecutive o)
    #pragma unroll
    for (int dp = 0; dp < 2; ++dp){
      const size_t rowbase = (((size_t)b*D_ + (d + dp))*H_ + (h0 + wv))*W_;
      #pragma unroll
      for (int nt = 0; nt < 2; ++nt){
        const size_t pix = (rowbase + nt*16 + l15)*64;
        #pragma unroll
        for (int mt = 0; mt < 4; ++mt){
          bf16 row[4];
          #pragma unroll
          for (int rg = 0; rg < 4; ++rg){
            float y = acc[dp][mt][nt][rg] + br[mt][rg];
            psum[mt][rg] += y;
            psq[mt][rg]  = fmaf(y, y, psq[mt][rg]);
            row[rg] = __float2bfloat16(y);
          }
          *(short4v*)&X2[pix + mt*16 + quad*4] = *(short4v*)row;
        }
      }
    }
  }

  // BN2 stats: reduce across l15 (16 lanes within each quad), atomics from l15==0
  #pragma unroll
  for (int mt = 0; mt < 4; ++mt)
    #pragma unroll
    for (int rg = 0; rg < 4; ++rg){
      float s1 = psum[mt][rg], s2 = psq[mt][rg];
      #pragma unroll
      for (int m = 1; m < 16; m <<= 1){
        s1 += __shfl_xor(s1, m, 64);
        s2 += __shfl_xor(s2, m, 64);
      }
      if (l15 == 0){
        int o = mt*16 + quad*4 + rg;
        atomicAdd(&stats[o], s1);
        atomicAdd(&stats[64 + o], s2);
      }
    }
}

// ---------------- in-place BN2+ReLU on channel-last x2 ----------------

__global__ void bnact_kernel(bf16* __restrict__ x, const float* __restrict__ ss){
  size_t i8 = (size_t)blockIdx.x*blockDim.x + threadIdx.x;
  if (i8 >= (size_t)B_*DHW_*8) return;   // 64ch/8 per thread
  int ob = ((int)(i8 & 7)) * 8;
  bf16* p = x + i8*8;
  short8 v = *(short8*)p;
  bf16* pv = (bf16*)&v;
  #pragma unroll
  for (int j = 0; j < 8; ++j){
    int o = ob + j;
    float f = fmaxf(fmaf(ss[o], __bfloat162float(pv[j]), ss[64 + o]), 0.f);
    pv[j] = __float2bfloat16(f);
  }
  *(short8*)p = v;
}

// ---------------- conv3 MFMA (R8, unchanged): + BN3 stats + min/max over d ----------------

template<int DCHUNK>
__global__ __launch_bounds__(256, 2)
void conv3mfma_kernel(const bf16* __restrict__ X, const bf16* __restrict__ WB,
                      const float* __restrict__ bias, float* __restrict__ stats,
                      bf16* __restrict__ minp, bf16* __restrict__ maxp){
  const int tid  = threadIdx.x;
  const int lane = tid & 63;
  const int wv   = tid >> 6;
  const int l15  = lane & 15;
  const int quad = lane >> 4;
  const int h0   = blockIdx.x * 4;
  const int d0   = blockIdx.y * DCHUNK;
  const int b    = blockIdx.z;

  __shared__ __align__(16) bf16 at[4][6][34][32];

  for (int e = tid; e < 4*6*2*32; e += 256){
    int ch = e & 31; int side = (e >> 5) & 1; int r = (e >> 6) % 6; int sl = (e >> 6) / 6;
    at[sl][r][side ? 33 : 0][ch] = __float2bfloat16(0.f);
  }

  f32x4 acc[2][2][4];
  float mmx[2][4][4], mmn[2][4][4];
  float brg[4];
  #pragma unroll
  for (int nt = 0; nt < 4; ++nt) brg[nt] = bias[nt*16 + l15];
  #pragma unroll
  for (int mh = 0; mh < 2; ++mh)
    #pragma unroll
    for (int nt = 0; nt < 4; ++nt)
      #pragma unroll
      for (int rg = 0; rg < 4; ++rg){ mmx[mh][nt][rg] = -FLT_MAX; mmn[mh][nt][rg] = FLT_MAX; }
  float psum[4] = {0.f,0.f,0.f,0.f}, psq[4] = {0.f,0.f,0.f,0.f};

  const int wlane = lane >> 2;
  const int cq    = lane & 3;

  for (int p = 0; p < DCHUNK/2; ++p){
    const int d = d0 + 2*p;
    #pragma unroll
    for (int dp = 0; dp < 2; ++dp)
      #pragma unroll
      for (int mh = 0; mh < 2; ++mh)
        #pragma unroll
        for (int nt = 0; nt < 4; ++nt)
          acc[dp][mh][nt] = (f32x4){0.f, 0.f, 0.f, 0.f};

    for (int ic = 0; ic < 2; ++ic){
      __syncthreads();
      for (int j = wv; j < 24; j += 4){
        int sl = j / 6, r = j - sl*6;
        int dd = d - 1 + sl, hh = h0 - 1 + r;
        if (dd >= 0 && dd < D_ && hh >= 0 && hh < H_){
          const bf16* rowp = X + (((size_t)b*D_ + dd)*H_ + hh)*W_*64 + ic*32 + cq*8;
          #pragma unroll
          for (int half = 0; half < 2; ++half)
            gl_lds16(rowp + (size_t)(wlane + half*16)*64, &at[sl][r][1 + half*16][0]);
        } else {
          short8 z = {0,0,0,0,0,0,0,0};
          #pragma unroll
          for (int half = 0; half < 2; ++half)
            *(short8*)(&at[sl][r][1 + half*16][0] + (size_t)lane*8) = z;
        }
      }
      __syncthreads();

      #pragma unroll
      for (int kd = 0; kd < 3; ++kd)
        #pragma unroll
        for (int kh = 0; kh < 3; ++kh)
          #pragma unroll
          for (int kw = 0; kw < 3; ++kw){
            const bf16* wb = WB + (size_t)((kd*3 + kh)*3 + kw)*64*64 + ic*32 + quad*8;
            short8 bfr[4];
            #pragma unroll
            for (int nt = 0; nt < 4; ++nt)
              bfr[nt] = *(const short8*)(wb + (nt*16 + l15)*64);
            #pragma unroll
            for (int dp = 0; dp < 2; ++dp){
              short8 af[2];
              #pragma unroll
              for (int mh = 0; mh < 2; ++mh)
                af[mh] = *(const short8*)&at[dp + kd][wv + kh][mh*16 + l15 + kw][quad*8];
              #pragma unroll
              for (int mh = 0; mh < 2; ++mh)
                #pragma unroll
                for (int nt = 0; nt < 4; ++nt)
                  acc[dp][mh][nt] = __builtin_amdgcn_mfma_f32_16x16x32_bf16(af[mh], bfr[nt], acc[dp][mh][nt], 0, 0, 0);
            }
          }
    }

    #pragma unroll
    for (int dp = 0; dp < 2; ++dp)
      #pragma unroll
      for (int mh = 0; mh < 2; ++mh)
        #pragma unroll
        for (int nt = 0; nt < 4; ++nt)
          #pragma unroll
          for (int rg = 0; rg < 4; ++rg){
            float y = acc[dp][mh][nt][rg] + brg[nt];
            psum[nt] += y;
            psq[nt]  = fmaf(y, y, psq[nt]);
            mmx[mh][nt][rg] = fmaxf(mmx[mh][nt][rg], y);
            mmn[mh][nt][rg] = fminf(mmn[mh][nt][rg], y);
          }
  }

  #pragma unroll
  for (int nt = 0; nt < 4; ++nt){
    float s1 = psum[nt], s2 = psq[nt];
    s1 += __shfl_xor(s1, 16, 64);  s2 += __shfl_xor(s2, 16, 64);
    s1 += __shfl_xor(s1, 32, 64);  s2 += __shfl_xor(s2, 32, 64);
    if (quad == 0){
      atomicAdd(&stats[nt*16 + l15], s1);
      atomicAdd(&stats[64 + nt*16 + l15], s2);
    }
  }

  const size_t slab = (size_t)blockIdx.y * OUTN_;
  const int h = h0 + wv;
  #pragma unroll
  for (int mh = 0; mh < 2; ++mh)
    #pragma unroll
    for (int nt = 0; nt < 4; ++nt){
      int o = nt*16 + l15;
      #pragma unroll
      for (int rg = 0; rg < 4; ++rg){
        int w = mh*16 + quad*4 + rg;
        size_t idx = slab + ((size_t)(b*64 + o))*HW_ + h*W_ + w;
        maxp[idx] = __float2bfloat16(mmx[mh][nt][rg]);
        minp[idx] = __float2bfloat16(mmn[mh][nt][rg]);
      }
    }
}

// ---------------- final: reduce slabs, apply BN3+ReLU via monotonicity ----------------

__global__ void bevreduce_kernel(const bf16* __restrict__ minp, const bf16* __restrict__ maxp,
                                 const float* __restrict__ ss, float* __restrict__ out, int nslab){
  int j = blockIdx.x*blockDim.x + threadIdx.x;
  if (j >= OUTN_) return;
  int o = (j >> 12) & 63;
  float mx = -FLT_MAX, mn = FLT_MAX;
  for (int s = 0; s < nslab; ++s){
    mx = fmaxf(mx, __bfloat162float(maxp[(size_t)s*OUTN_ + j]));
    mn = fminf(mn, __bfloat162float(minp[(size_t)s*OUTN_ + j]));
  }
  float a = ss[o], sh = ss[64 + o];
  float v = (a >= 0.f) ? mx : mn;
  out[j] = fmaxf(fmaf(a, v, sh), 0.f);
}

// ---------------- BN finalize ----------------

__global__ void finalize_kernel(const float* __restrict__ stats, const float* __restrict__ gamma,
                                const float* __restrict__ beta, float* __restrict__ ss, int C){
  int c = threadIdx.x;
  if (c >= C) return;
  const float invCnt = 1.0f / (float)((size_t)B_*DHW_);
  float mean = stats[c] * invCnt;
  float var  = stats[C + c] * invCnt - mean*mean;
  float a = gamma[c] * rsqrtf(var + EPSV);
  ss[c]     = a;
  ss[C + c] = beta[c] - mean*a;
}

// ---------------- launch ----------------

extern "C" void kernel_launch(void* const* d_in, const int* in_sizes, int n_in,
                              void* d_out, int out_size, void* d_ws, size_t ws_size,
                              hipStream_t stream){
  const float* pc  = (const float*)d_in[0];
  const float* w1  = (const float*)d_in[1];
  const float* b1  = (const float*)d_in[2];
  const float* g1  = (const float*)d_in[3];
  const float* be1 = (const float*)d_in[4];
  const float* w2  = (const float*)d_in[5];
  const float* b2  = (const float*)d_in[6];
  const float* g2  = (const float*)d_in[7];
  const float* be2 = (const float*)d_in[8];
  const float* w3  = (const float*)d_in[9];
  const float* b3  = (const float*)d_in[10];
  const float* g3  = (const float*)d_in[11];
  const float* be3 = (const float*)d_in[12];
  const int N = in_sizes[0] / 6;  // (B=2, 3, N)
  float* out = (float*)d_out;

  char* wsb = (char*)d_ws;
  size_t off = 0;
  auto alloc = [&](size_t bytes)->char*{
    off = (off + 255) & ~(size_t)255;
    char* p = wsb + off; off += bytes; return p;
  };
  float* g0   = (float*)alloc((size_t)B_*DHW_*4);   // 4 MB
  float* wr1  = (float*)alloc(864*4);               // [27k][32o] fp32
  float* wr2  = (float*)alloc(55296*4);             // fp32 (fallback fused12)
  bf16*  wr2b = (bf16*) alloc(55296*2);             // [tap][64o][32i] bf16
  bf16*  wr3b = (bf16*) alloc(110592*2);            // [tap][64o][64i] bf16
  float* mins = (float*)alloc(8*4);
  float* st   = (float*)alloc(3*128*4);
  float* ss   = (float*)alloc(3*128*4);

  constexpr int DCHUNK = 16;
  constexpr int NSLAB  = D_ / DCHUNK;               // 8
  const size_t SX1  = (size_t)B_*DHW_*32*2;         // 64 MiB channel-last bf16
  const size_t SX2  = (size_t)B_*DHW_*64*2;         // 128 MiB channel-last bf16
  const size_t SMM  = (size_t)NSLAB*OUTN_*2;        // 8 MiB per min/max array

  // regionR: x1 (64MiB) aliases minp/maxp (16MiB) — disjoint lifetimes
  // (x1: conv1act..conv2mfma; min/max: conv3mfma..bevreduce).
  const size_t prefixEnd = (off + 255) & ~(size_t)255;
  const bool useMfma2 = ws_size >= prefixEnd + SX1 + SX2 + 1024;

  char* regionR = alloc(useMfma2 ? SX1 : 2*SMM);
  bf16* maxp = (bf16*)regionR;
  bf16* minp = (bf16*)(regionR + SMM);
  bf16* x1   = (bf16*)regionR;
  bf16* x2   = (bf16*)alloc(SX2);

  // prologue
  zero_kernel<<<(B_*DHW_ + 255)/256, 256, 0, stream>>>(g0, B_*DHW_);
  zero_kernel<<<2, 256, 0, stream>>>(st, 3*128);
  min_kernel<<<B_*3, 256, 0, stream>>>(pc, mins, N);
  scatter_kernel<<<(B_*N + 255)/256, 256, 0, stream>>>(pc, mins, g0, N);
  reorder_kernel<<<(864 + 255)/256, 256, 0, stream>>>(w1, wr1, 1, 32);
  reorder_kernel<<<(55296 + 255)/256, 256, 0, stream>>>(w2, wr2, 32, 64);
  reorder2b_kernel<<<(55296 + 255)/256, 256, 0, stream>>>(w2, wr2b);
  reorder3b_kernel<<<(110592 + 255)/256, 256, 0, stream>>>(w3, wr3b);

  dim3 cgrid(16, 128, 2);                           // (8h-tiles, d, b)
  dim3 mgrid(32, NSLAB, 2);                         // (4h-tiles, 16d-slabs, b)

  convstats_kernel<<<cgrid, 256, 0, stream>>>(g0, wr1, b1, st);
  finalize_kernel<<<1, 64, 0, stream>>>(st, g1, be1, ss, 32);

  if (useMfma2){
    conv1act_kernel<<<cgrid, 256, 0, stream>>>(g0, wr1, b1, ss, x1);
    conv2mfma_kernel<DCHUNK><<<mgrid, 256, 0, stream>>>(x1, wr2b, b2, x2, st + 128);
  } else {
    fused12_kernel<<<cgrid, 256, 0, stream>>>(g0, wr1, b1, ss, wr2, b2, x2, st + 128);
  }
  finalize_kernel<<<1, 64, 0, stream>>>(st + 128, g2, be2, ss + 128, 64);

  bnact_kernel<<<(int)(((size_t)B_*DHW_*8 + 255)/256), 256, 0, stream>>>(x2, ss + 128);

  conv3mfma_kernel<DCHUNK><<<mgrid, 256, 0, stream>>>(x2, wr3b, b3, st + 256, minp, maxp);
  finalize_kernel<<<1, 64, 0, stream>>>(st + 256, g3, be3, ss + 256, 64);
  bevreduce_kernel<<<(OUTN_ + 255)/256, 256, 0, stream>>>(minp, maxp, ss + 256, out, NSLAB);
}

// Round 10
// 1370.958 us; speedup vs baseline: 9.3282x; 1.6352x over previous
//
#include <hip/hip_runtime.h>
#include <hip/hip_bf16.h>
#include <float.h>

// LiDAR BEV pipeline (fp32 I/O):
//   voxelize -> conv3d(1->32)+BN+ReLU -> conv3d(32->64)+BN+ReLU -> conv3d(64->64)+BN+ReLU -> max over D
// R9: 2.24ms. convstats was an ATOMIC-CONTENTION stall (796us, VALUBusy 3.9%: 262K
// device-scope RMWs on 16 cache lines; conv1act with identical body but no atomics
// never shows). R10: (1) drop convstats -- conv1act now emits raw y1 + BN1 stats,
// BN1+ReLU applied by in-place bnact<32>; (2) all BN stats go through 128-bucket
// partial arrays (contention /128), summed in finalize.

#define VOXEL 0.0625f
#define D_ 128
#define H_ 128
#define W_ 32
#define HW_ (H_*W_)      // 4096
#define DHW_ (D_*H_*W_)  // 524288
#define B_ 2
#define EPSV 1e-5f
#define OUTN_ (B_*64*HW_) // 524288
#define NBUCK 128         // stats buckets (x128 less atomic contention)

typedef __hip_bfloat16 bf16;
typedef __attribute__((ext_vector_type(8))) short short8;   // 8 bf16
typedef __attribute__((ext_vector_type(4))) short short4v;  // 4 bf16
typedef __attribute__((ext_vector_type(4))) float f32x4;

__device__ inline void gl_lds16(const void* g, void* l){
  // async global->LDS, 16B per lane; LDS dest = base + lane*16 (wave-uniform base)
  __builtin_amdgcn_global_load_lds(
      (const __attribute__((address_space(1))) unsigned int*)g,
      (__attribute__((address_space(3))) unsigned int*)l, 16, 0, 0);
}

// ---------------- init ----------------

__global__ void zero_kernel(float* __restrict__ p, int n){
  int i = blockIdx.x*blockDim.x + threadIdx.x;
  if (i < n) p[i] = 0.f;
}

// ---------------- voxelize ----------------

__global__ void min_kernel(const float* __restrict__ pc, float* __restrict__ mins, int N){
  const float* base = pc + (size_t)blockIdx.x * N;
  float m = FLT_MAX;
  for (int j = threadIdx.x; j < N; j += blockDim.x){
    float v = base[j];
    if (v != v) v = 0.f;          // NaN -> 0, matching reference
    m = fminf(m, v);
  }
  for (int off = 32; off > 0; off >>= 1)
    m = fminf(m, __shfl_xor(m, off, 64));
  __shared__ float red[4];
  int wave = threadIdx.x >> 6;
  if ((threadIdx.x & 63) == 0) red[wave] = m;
  __syncthreads();
  if (threadIdx.x == 0){
    float r = red[0];
    for (int k = 1; k < (int)(blockDim.x >> 6); ++k) r = fminf(r, red[k]);
    mins[blockIdx.x] = r;
  }
}

__global__ void scatter_kernel(const float* __restrict__ pc, const float* __restrict__ mins,
                               float* __restrict__ grid, int N){
  int idx = blockIdx.x*blockDim.x + threadIdx.x;
  if (idx >= B_*N) return;
  int b = idx / N, n = idx - b*N;
  float x = pc[((size_t)b*3 + 0)*N + n];
  float y = pc[((size_t)b*3 + 1)*N + n];
  float z = pc[((size_t)b*3 + 2)*N + n];
  if (x != x) x = 0.f;
  if (y != y) y = 0.f;
  if (z != z) z = 0.f;
  int ix = (int)floorf((x - mins[b*3+0]) / VOXEL);
  int iy = (int)floorf((y - mins[b*3+1]) / VOXEL);
  int iz = (int)floorf((z - mins[b*3+2]) / VOXEL);
  ix = min(max(ix, 0), D_-1);
  iy = min(max(iy, 0), H_-1);
  iz = min(max(iz, 0), W_-1);
  grid[(size_t)b*DHW_ + (size_t)ix*HW_ + iy*W_ + iz] = 1.0f;
}

// ---------------- weight reorders ----------------

__global__ void reorder_kernel(const float* __restrict__ w, float* __restrict__ wr, int CIN, int COUT){
  int idx = blockIdx.x*blockDim.x + threadIdx.x;
  int total = COUT*CIN*27;
  if (idx >= total) return;
  int o = idx / (CIN*27);
  int rem = idx - o*(CIN*27);
  int i = rem / 27;
  int k = rem - i*27;
  wr[(i*27 + k)*COUT + o] = w[idx];
}

// w3 (64,64,3,3,3) fp32 -> [tap][o][64 i] bf16
__global__ void reorder3b_kernel(const float* __restrict__ w, bf16* __restrict__ wb){
  int idx = blockIdx.x*blockDim.x + threadIdx.x;
  if (idx >= 64*64*27) return;
  int o = idx / (64*27);
  int rem = idx - o*(64*27);
  int i = rem / 27;
  int tap = rem - i*27;
  wb[((size_t)tap*64 + o)*64 + i] = __float2bfloat16(w[idx]);
}

// w2 (64,32,3,3,3) fp32 -> [tap][o][32 i] bf16
__global__ void reorder2b_kernel(const float* __restrict__ w, bf16* __restrict__ wb){
  int idx = blockIdx.x*blockDim.x + threadIdx.x;
  if (idx >= 64*32*27) return;
  int o = idx / (32*27);
  int rem = idx - o*(32*27);
  int i = rem / 27;
  int tap = rem - i*27;
  wb[((size_t)tap*64 + o)*32 + i] = __float2bfloat16(w[idx]);
}

// ---------------- fp32 conv inner (conv1-class kernels) ----------------

template<int HT, int OPT, int COUT>
__device__ inline void conv_inner(float (*xs)[HT+2][34], float (*wsm)[COUT],
                                  int w, int og, float (*acc)[OPT]){
  #pragma unroll
  for (int kd = 0; kd < 3; ++kd){
    float xr[HT+2][3];
    #pragma unroll
    for (int r = 0; r < HT+2; ++r)
      #pragma unroll
      for (int c = 0; c < 3; ++c)
        xr[r][c] = xs[kd][r][w + c];
    #pragma unroll
    for (int kh = 0; kh < 3; ++kh)
      #pragma unroll
      for (int kw = 0; kw < 3; ++kw){
        const float* wp = &wsm[kd*9 + kh*3 + kw][og*OPT];
        float wv[OPT];
        #pragma unroll
        for (int oo = 0; oo < OPT; ++oo) wv[oo] = wp[oo];
        #pragma unroll
        for (int h = 0; h < HT; ++h){
          float xv = xr[h + kh][kw];
          #pragma unroll
          for (int oo = 0; oo < OPT; ++oo)
            acc[h][oo] = fmaf(xv, wv[oo], acc[h][oo]);
        }
      }
  }
}

// ---------------- conv1 BN stats only (fallback path) ----------------

__global__ __launch_bounds__(256)
void convstats_kernel(const float* __restrict__ X, const float* __restrict__ WR,
                      const float* __restrict__ bias, float* __restrict__ stats){
  const int tid = threadIdx.x;
  const int w   = tid & 31;
  const int og  = tid >> 5;
  const int h0  = blockIdx.x * 8;
  const int d   = blockIdx.y;
  const int b   = blockIdx.z;
  const int bucket = d & (NBUCK - 1);

  __shared__ float xs[3][10][34];
  __shared__ float wsm[27][32];

  float acc[8][4];
  #pragma unroll
  for (int h = 0; h < 8; ++h)
    #pragma unroll
    for (int oo = 0; oo < 4; ++oo) acc[h][oo] = 0.f;

  for (int e = tid; e < 27*32; e += 256)
    ((float*)wsm)[e] = WR[e];
  for (int e = tid; e < 960; e += 256){
    int ds = e / 320; int rem = e - ds*320; int r = rem >> 5; int ww = rem & 31;
    int dd = d + ds - 1, hh = h0 + r - 1;
    float v = 0.f;
    if (dd >= 0 && dd < D_ && hh >= 0 && hh < H_)
      v = X[((size_t)b*D_ + dd)*HW_ + hh*W_ + ww];
    xs[ds][r][ww + 1] = v;
  }
  if (tid < 30){ int ds = tid/10, r = tid - ds*10; xs[ds][r][0] = 0.f; xs[ds][r][33] = 0.f; }
  __syncthreads();
  conv_inner<8, 4, 32>(xs, wsm, w, og, acc);

  #pragma unroll
  for (int oo = 0; oo < 4; ++oo){
    int o = og*4 + oo;
    float bo = bias[o];
    float s1 = 0.f, s2 = 0.f;
    #pragma unroll
    for (int h = 0; h < 8; ++h){
      float y = acc[h][oo] + bo;
      s1 += y;
      s2 = fmaf(y, y, s2);
    }
    for (int m = 16; m > 0; m >>= 1){
      s1 += __shfl_xor(s1, m, 32);
      s2 += __shfl_xor(s2, m, 32);
    }
    if (w == 0){
      atomicAdd(&stats[bucket*128 + o], s1);
      atomicAdd(&stats[bucket*128 + 32 + o], s2);
    }
  }
}

// ---------------- conv1 -> RAW x1 channel-last bf16 [b][d][h][w][32] + BN1 stats ----------------

__global__ __launch_bounds__(256)
void conv1act_kernel(const float* __restrict__ X, const float* __restrict__ WR,
                     const float* __restrict__ bias, bf16* __restrict__ X1,
                     float* __restrict__ stats){
  const int tid = threadIdx.x;
  const int w   = tid & 31;
  const int og  = tid >> 5;
  const int h0  = blockIdx.x * 8;
  const int d   = blockIdx.y;
  const int b   = blockIdx.z;
  const int bucket = d & (NBUCK - 1);

  __shared__ float xs[3][10][34];
  __shared__ float wsm[27][32];

  float acc[8][4];
  #pragma unroll
  for (int h = 0; h < 8; ++h)
    #pragma unroll
    for (int oo = 0; oo < 4; ++oo) acc[h][oo] = 0.f;

  for (int e = tid; e < 27*32; e += 256)
    ((float*)wsm)[e] = WR[e];
  for (int e = tid; e < 960; e += 256){
    int ds = e / 320; int rem = e - ds*320; int r = rem >> 5; int ww = rem & 31;
    int dd = d + ds - 1, hh = h0 + r - 1;
    float v = 0.f;
    if (dd >= 0 && dd < D_ && hh >= 0 && hh < H_)
      v = X[((size_t)b*D_ + dd)*HW_ + hh*W_ + ww];
    xs[ds][r][ww + 1] = v;
  }
  if (tid < 30){ int ds = tid/10, r = tid - ds*10; xs[ds][r][0] = 0.f; xs[ds][r][33] = 0.f; }
  __syncthreads();
  conv_inner<8, 4, 32>(xs, wsm, w, og, acc);

  float bo[4], psum[4], psq[4];
  #pragma unroll
  for (int oo = 0; oo < 4; ++oo){
    bo[oo] = bias[og*4 + oo]; psum[oo] = 0.f; psq[oo] = 0.f;
  }
  #pragma unroll
  for (int h = 0; h < 8; ++h){
    bf16 row[4];
    #pragma unroll
    for (int oo = 0; oo < 4; ++oo){
      float y = acc[h][oo] + bo[oo];
      row[oo] = __float2bfloat16(y);
      psum[oo] += y;
      psq[oo]  = fmaf(y, y, psq[oo]);
    }
    *(short4v*)&X1[((((size_t)b*D_ + d)*H_ + (h0 + h))*W_ + w)*32 + og*4] = *(short4v*)row;
  }
  #pragma unroll
  for (int oo = 0; oo < 4; ++oo){
    float s1 = psum[oo], s2 = psq[oo];
    for (int m = 16; m > 0; m >>= 1){
      s1 += __shfl_xor(s1, m, 32);
      s2 += __shfl_xor(s2, m, 32);
    }
    if (w == 0){
      int o = og*4 + oo;
      atomicAdd(&stats[bucket*128 + o], s1);
      atomicAdd(&stats[bucket*128 + 32 + o], s2);
    }
  }
}

// ---------------- fused12 (fp32 fallback path, writes raw x2 + BN2 stats) ----------------

__global__ __launch_bounds__(256)
void fused12_kernel(const float* __restrict__ G0, const float* __restrict__ WR1,
                    const float* __restrict__ B1, const float* __restrict__ SS1,
                    const float* __restrict__ WR2, const float* __restrict__ B2,
                    bf16* __restrict__ X2, float* __restrict__ stats){
  const int tid = threadIdx.x;
  const int w   = tid & 31;
  const int og  = tid >> 5;
  const int h0  = blockIdx.x * 8;
  const int d   = blockIdx.y;
  const int b   = blockIdx.z;
  const int bucket = d & (NBUCK - 1);

  __shared__ float gs[5][12][34];
  __shared__ float w1s[32][27];
  __shared__ float xs[3][10][34];
  __shared__ float wsm[27][64];

  for (int e = tid; e < 5*12*34; e += 256){
    int ds = e / 408; int rem = e - ds*408; int r = rem / 34; int c = rem - r*34;
    int dd = d - 2 + ds, hh = h0 - 2 + r, ww = c - 1;
    float v = 0.f;
    if (c >= 1 && c <= 32 && dd >= 0 && dd < D_ && hh >= 0 && hh < H_)
      v = G0[((size_t)b*D_ + dd)*HW_ + hh*W_ + ww];
    gs[ds][r][c] = v;
  }
  for (int e = tid; e < 864; e += 256){
    int i = e/27, k = e - 27*i;
    w1s[i][k] = WR1[k*32 + i];
  }

  float acc[8][8];
  #pragma unroll
  for (int h = 0; h < 8; ++h)
    #pragma unroll
    for (int oo = 0; oo < 8; ++oo) acc[h][oo] = 0.f;

  for (int i = 0; i < 32; ++i){
    __syncthreads();
    float a1 = SS1[i];
    float f1 = fmaf(a1, B1[i], SS1[32 + i]);
    for (int e = tid; e < 1020; e += 256){
      int ds = e / 340; int rem = e - ds*340; int r = rem / 34; int c = rem - r*34;
      float v = 0.f;
      int dd = d - 1 + ds, hh = h0 - 1 + r;
      if (c >= 1 && c <= 32 && dd >= 0 && dd < D_ && hh >= 0 && hh < H_){
        float s = 0.f;
        #pragma unroll
        for (int kd = 0; kd < 3; ++kd)
          #pragma unroll
          for (int kh = 0; kh < 3; ++kh)
            #pragma unroll
            for (int kw = 0; kw < 3; ++kw)
              s = fmaf(gs[ds+kd][r+kh][c-1+kw], w1s[i][kd*9+kh*3+kw], s);
        v = fmaxf(fmaf(a1, s, f1), 0.f);
      }
      xs[ds][r][c] = v;
    }
    for (int e = tid; e < 27*64; e += 256)
      ((float*)wsm)[e] = WR2[i*27*64 + e];
    __syncthreads();
    conv_inner<8, 8, 64>(xs, wsm, w, og, acc);
  }

  float bo[8], psum[8], psq[8];
  #pragma unroll
  for (int oo = 0; oo < 8; ++oo){ bo[oo] = B2[og*8 + oo]; psum[oo] = 0.f; psq[oo] = 0.f; }
  #pragma unroll
  for (int h = 0; h < 8; ++h){
    bf16 row[8];
    #pragma unroll
    for (int oo = 0; oo < 8; ++oo){
      float y = acc[h][oo] + bo[oo];
      row[oo] = __float2bfloat16(y);
      psum[oo] += y;
      psq[oo]  = fmaf(y, y, psq[oo]);
    }
    *(short8*)&X2[((((size_t)b*D_ + d)*H_ + (h0 + h))*W_ + w)*64 + og*8] = *(short8*)row;
  }
  #pragma unroll
  for (int oo = 0; oo < 8; ++oo){
    float s1 = psum[oo], s2 = psq[oo];
    for (int m = 16; m > 0; m >>= 1){
      s1 += __shfl_xor(s1, m, 32);
      s2 += __shfl_xor(s2, m, 32);
    }
    if (w == 0){
      atomicAdd(&stats[bucket*128 + og*8 + oo], s1);
      atomicAdd(&stats[bucket*128 + 64 + og*8 + oo], s2);
    }
  }
}

// ---------------- conv2 MFMA: weights=A (M=64 o), activations=B (N=32 w) ----------------

template<int DCHUNK>
__global__ __launch_bounds__(256, 2)
void conv2mfma_kernel(const bf16* __restrict__ X1, const bf16* __restrict__ WB,
                      const float* __restrict__ B2, bf16* __restrict__ X2,
                      float* __restrict__ stats){
  const int tid  = threadIdx.x;
  const int lane = tid & 63;
  const int wv   = tid >> 6;        // wave id = h-row
  const int l15  = lane & 15;
  const int quad = lane >> 4;
  const int h0   = blockIdx.x * 4;
  const int d0   = blockIdx.y * DCHUNK;
  const int b    = blockIdx.z;
  const int bucket = (blockIdx.x | (blockIdx.y << 5)) & (NBUCK - 1);

  __shared__ __align__(16) bf16 at[4][6][34][32];   // 52,224 B

  for (int e = tid; e < 4*6*2*32; e += 256){
    int ch = e & 31; int side = (e >> 5) & 1; int r = (e >> 6) % 6; int sl = (e >> 6) / 6;
    at[sl][r][side ? 33 : 0][ch] = __float2bfloat16(0.f);
  }

  f32x4 acc[2][4][2];               // [dp][mt][nt]
  float br[4][4], psum[4][4], psq[4][4];
  #pragma unroll
  for (int mt = 0; mt < 4; ++mt)
    #pragma unroll
    for (int rg = 0; rg < 4; ++rg){
      br[mt][rg] = B2[mt*16 + quad*4 + rg];
      psum[mt][rg] = 0.f; psq[mt][rg] = 0.f;
    }

  const int wlane = lane >> 2;
  const int cq    = lane & 3;

  for (int p = 0; p < DCHUNK/2; ++p){
    const int d = d0 + 2*p;
    #pragma unroll
    for (int dp = 0; dp < 2; ++dp)
      #pragma unroll
      for (int mt = 0; mt < 4; ++mt)
        #pragma unroll
        for (int nt = 0; nt < 2; ++nt)
          acc[dp][mt][nt] = (f32x4){0.f, 0.f, 0.f, 0.f};

    __syncthreads();
    for (int j = wv; j < 24; j += 4){
      int sl = j / 6, r = j - sl*6;
      int dd = d - 1 + sl, hh = h0 - 1 + r;
      if (dd >= 0 && dd < D_ && hh >= 0 && hh < H_){
        const bf16* rowp = X1 + (((size_t)b*D_ + dd)*H_ + hh)*W_*32 + cq*8;
        #pragma unroll
        for (int half = 0; half < 2; ++half)
          gl_lds16(rowp + (size_t)(wlane + half*16)*32, &at[sl][r][1 + half*16][0]);
      } else {
        short8 z = {0,0,0,0,0,0,0,0};
        #pragma unroll
        for (int half = 0; half < 2; ++half)
          *(short8*)(&at[sl][r][1 + half*16][0] + (size_t)lane*8) = z;
      }
    }
    __syncthreads();

    #pragma unroll
    for (int kd = 0; kd < 3; ++kd)
      #pragma unroll
      for (int kh = 0; kh < 3; ++kh)
        #pragma unroll
        for (int kw = 0; kw < 3; ++kw){
          const bf16* wb = WB + (size_t)((kd*3 + kh)*3 + kw)*64*32 + quad*8;
          short8 afw[4];
          #pragma unroll
          for (int mt = 0; mt < 4; ++mt)
            afw[mt] = *(const short8*)(wb + (mt*16 + l15)*32);
          #pragma unroll
          for (int dp = 0; dp < 2; ++dp){
            short8 bfa[2];
            #pragma unroll
            for (int nt = 0; nt < 2; ++nt)
              bfa[nt] = *(const short8*)&at[dp + kd][wv + kh][nt*16 + l15 + kw][quad*8];
            #pragma unroll
            for (int mt = 0; mt < 4; ++mt)
              #pragma unroll
              for (int nt = 0; nt < 2; ++nt)
                acc[dp][mt][nt] = __builtin_amdgcn_mfma_f32_16x16x32_bf16(afw[mt], bfa[nt], acc[dp][mt][nt], 0, 0, 0);
          }
        }

    // pair epilogue: bias, stats, coalesced 8B stores (4 consecutive o)
    #pragma unroll
    for (int dp = 0; dp < 2; ++dp){
      const size_t rowbase = (((size_t)b*D_ + (d + dp))*H_ + (h0 + wv))*W_;
      #pragma unroll
      for (int nt = 0; nt < 2; ++nt){
        const size_t pix = (rowbase + nt*16 + l15)*64;
        #pragma unroll
        for (int mt = 0; mt < 4; ++mt){
          bf16 row[4];
          #pragma unroll
          for (int rg = 0; rg < 4; ++rg){
            float y = acc[dp][mt][nt][rg] + br[mt][rg];
            psum[mt][rg] += y;
            psq[mt][rg]  = fmaf(y, y, psq[mt][rg]);
            row[rg] = __float2bfloat16(y);
          }
          *(short4v*)&X2[pix + mt*16 + quad*4] = *(short4v*)row;
        }
      }
    }
  }

  // BN2 stats: reduce across l15, bucketed atomics from l15==0
  #pragma unroll
  for (int mt = 0; mt < 4; ++mt)
    #pragma unroll
    for (int rg = 0; rg < 4; ++rg){
      float s1 = psum[mt][rg], s2 = psq[mt][rg];
      #pragma unroll
      for (int m = 1; m < 16; m <<= 1){
        s1 += __shfl_xor(s1, m, 64);
        s2 += __shfl_xor(s2, m, 64);
      }
      if (l15 == 0){
        int o = mt*16 + quad*4 + rg;
        atomicAdd(&stats[bucket*128 + o], s1);
        atomicAdd(&stats[bucket*128 + 64 + o], s2);
      }
    }
}

// ---------------- in-place BN+ReLU on channel-last tensor ----------------

template<int C>
__global__ void bnact_kernel(bf16* __restrict__ x, const float* __restrict__ ss){
  size_t i8 = (size_t)blockIdx.x*blockDim.x + threadIdx.x;
  if (i8 >= (size_t)B_*DHW_*(C/8)) return;
  int ob = ((int)(i8 & (C/8 - 1))) * 8;
  bf16* p = x + i8*8;
  short8 v = *(short8*)p;
  bf16* pv = (bf16*)&v;
  #pragma unroll
  for (int j = 0; j < 8; ++j){
    int o = ob + j;
    float f = fmaxf(fmaf(ss[o], __bfloat162float(pv[j]), ss[C + o]), 0.f);
    pv[j] = __float2bfloat16(f);
  }
  *(short8*)p = v;
}

// ---------------- conv3 MFMA: + BN3 stats + min/max over d ----------------

template<int DCHUNK>
__global__ __launch_bounds__(256, 2)
void conv3mfma_kernel(const bf16* __restrict__ X, const bf16* __restrict__ WB,
                      const float* __restrict__ bias, float* __restrict__ stats,
                      bf16* __restrict__ minp, bf16* __restrict__ maxp){
  const int tid  = threadIdx.x;
  const int lane = tid & 63;
  const int wv   = tid >> 6;
  const int l15  = lane & 15;
  const int quad = lane >> 4;
  const int h0   = blockIdx.x * 4;
  const int d0   = blockIdx.y * DCHUNK;
  const int b    = blockIdx.z;
  const int bucket = (blockIdx.x | (blockIdx.y << 5)) & (NBUCK - 1);

  __shared__ __align__(16) bf16 at[4][6][34][32];

  for (int e = tid; e < 4*6*2*32; e += 256){
    int ch = e & 31; int side = (e >> 5) & 1; int r = (e >> 6) % 6; int sl = (e >> 6) / 6;
    at[sl][r][side ? 33 : 0][ch] = __float2bfloat16(0.f);
  }

  f32x4 acc[2][2][4];
  float mmx[2][4][4], mmn[2][4][4];
  float brg[4];
  #pragma unroll
  for (int nt = 0; nt < 4; ++nt) brg[nt] = bias[nt*16 + l15];
  #pragma unroll
  for (int mh = 0; mh < 2; ++mh)
    #pragma unroll
    for (int nt = 0; nt < 4; ++nt)
      #pragma unroll
      for (int rg = 0; rg < 4; ++rg){ mmx[mh][nt][rg] = -FLT_MAX; mmn[mh][nt][rg] = FLT_MAX; }
  float psum[4] = {0.f,0.f,0.f,0.f}, psq[4] = {0.f,0.f,0.f,0.f};

  const int wlane = lane >> 2;
  const int cq    = lane & 3;

  for (int p = 0; p < DCHUNK/2; ++p){
    const int d = d0 + 2*p;
    #pragma unroll
    for (int dp = 0; dp < 2; ++dp)
      #pragma unroll
      for (int mh = 0; mh < 2; ++mh)
        #pragma unroll
        for (int nt = 0; nt < 4; ++nt)
          acc[dp][mh][nt] = (f32x4){0.f, 0.f, 0.f, 0.f};

    for (int ic = 0; ic < 2; ++ic){
      __syncthreads();
      for (int j = wv; j < 24; j += 4){
        int sl = j / 6, r = j - sl*6;
        int dd = d - 1 + sl, hh = h0 - 1 + r;
        if (dd >= 0 && dd < D_ && hh >= 0 && hh < H_){
          const bf16* rowp = X + (((size_t)b*D_ + dd)*H_ + hh)*W_*64 + ic*32 + cq*8;
          #pragma unroll
          for (int half = 0; half < 2; ++half)
            gl_lds16(rowp + (size_t)(wlane + half*16)*64, &at[sl][r][1 + half*16][0]);
        } else {
          short8 z = {0,0,0,0,0,0,0,0};
          #pragma unroll
          for (int half = 0; half < 2; ++half)
            *(short8*)(&at[sl][r][1 + half*16][0] + (size_t)lane*8) = z;
        }
      }
      __syncthreads();

      #pragma unroll
      for (int kd = 0; kd < 3; ++kd)
        #pragma unroll
        for (int kh = 0; kh < 3; ++kh)
          #pragma unroll
          for (int kw = 0; kw < 3; ++kw){
            const bf16* wb = WB + (size_t)((kd*3 + kh)*3 + kw)*64*64 + ic*32 + quad*8;
            short8 bfr[4];
            #pragma unroll
            for (int nt = 0; nt < 4; ++nt)
              bfr[nt] = *(const short8*)(wb + (nt*16 + l15)*64);
            #pragma unroll
            for (int dp = 0; dp < 2; ++dp){
              short8 af[2];
              #pragma unroll
              for (int mh = 0; mh < 2; ++mh)
                af[mh] = *(const short8*)&at[dp + kd][wv + kh][mh*16 + l15 + kw][quad*8];
              #pragma unroll
              for (int mh = 0; mh < 2; ++mh)
                #pragma unroll
                for (int nt = 0; nt < 4; ++nt)
                  acc[dp][mh][nt] = __builtin_amdgcn_mfma_f32_16x16x32_bf16(af[mh], bfr[nt], acc[dp][mh][nt], 0, 0, 0);
            }
          }
    }

    #pragma unroll
    for (int dp = 0; dp < 2; ++dp)
      #pragma unroll
      for (int mh = 0; mh < 2; ++mh)
        #pragma unroll
        for (int nt = 0; nt < 4; ++nt)
          #pragma unroll
          for (int rg = 0; rg < 4; ++rg){
            float y = acc[dp][mh][nt][rg] + brg[nt];
            psum[nt] += y;
            psq[nt]  = fmaf(y, y, psq[nt]);
            mmx[mh][nt][rg] = fmaxf(mmx[mh][nt][rg], y);
            mmn[mh][nt][rg] = fminf(mmn[mh][nt][rg], y);
          }
  }

  #pragma unroll
  for (int nt = 0; nt < 4; ++nt){
    float s1 = psum[nt], s2 = psq[nt];
    s1 += __shfl_xor(s1, 16, 64);  s2 += __shfl_xor(s2, 16, 64);
    s1 += __shfl_xor(s1, 32, 64);  s2 += __shfl_xor(s2, 32, 64);
    if (quad == 0){
      atomicAdd(&stats[bucket*128 + nt*16 + l15], s1);
      atomicAdd(&stats[bucket*128 + 64 + nt*16 + l15], s2);
    }
  }

  const size_t slab = (size_t)blockIdx.y * OUTN_;
  const int h = h0 + wv;
  #pragma unroll
  for (int mh = 0; mh < 2; ++mh)
    #pragma unroll
    for (int nt = 0; nt < 4; ++nt){
      int o = nt*16 + l15;
      #pragma unroll
      for (int rg = 0; rg < 4; ++rg){
        int w = mh*16 + quad*4 + rg;
        size_t idx = slab + ((size_t)(b*64 + o))*HW_ + h*W_ + w;
        maxp[idx] = __float2bfloat16(mmx[mh][nt][rg]);
        minp[idx] = __float2bfloat16(mmn[mh][nt][rg]);
      }
    }
}

// ---------------- final: reduce slabs, apply BN3+ReLU via monotonicity ----------------

__global__ void bevreduce_kernel(const bf16* __restrict__ minp, const bf16* __restrict__ maxp,
                                 const float* __restrict__ ss, float* __restrict__ out, int nslab){
  int j = blockIdx.x*blockDim.x + threadIdx.x;
  if (j >= OUTN_) return;
  int o = (j >> 12) & 63;
  float mx = -FLT_MAX, mn = FLT_MAX;
  for (int s = 0; s < nslab; ++s){
    mx = fmaxf(mx, __bfloat162float(maxp[(size_t)s*OUTN_ + j]));
    mn = fminf(mn, __bfloat162float(minp[(size_t)s*OUTN_ + j]));
  }
  float a = ss[o], sh = ss[64 + o];
  float v = (a >= 0.f) ? mx : mn;   // relu(a*z+s) monotone in z, direction sign(a)
  out[j] = fmaxf(fmaf(a, v, sh), 0.f);
}

// ---------------- BN finalize: sum buckets, scale/shift ----------------

__global__ void finalize_kernel(const float* __restrict__ stb, const float* __restrict__ gamma,
                                const float* __restrict__ beta, float* __restrict__ ss, int C){
  int c = threadIdx.x;
  if (c >= C) return;
  float s1 = 0.f, s2 = 0.f;
  for (int k = 0; k < NBUCK; ++k){
    s1 += stb[k*128 + c];
    s2 += stb[k*128 + C + c];
  }
  const float invCnt = 1.0f / (float)((size_t)B_*DHW_);
  float mean = s1 * invCnt;
  float var  = s2 * invCnt - mean*mean;
  float a = gamma[c] * rsqrtf(var + EPSV);
  ss[c]     = a;
  ss[C + c] = beta[c] - mean*a;
}

// ---------------- launch ----------------

extern "C" void kernel_launch(void* const* d_in, const int* in_sizes, int n_in,
                              void* d_out, int out_size, void* d_ws, size_t ws_size,
                              hipStream_t stream){
  const float* pc  = (const float*)d_in[0];
  const float* w1  = (const float*)d_in[1];
  const float* b1  = (const float*)d_in[2];
  const float* g1  = (const float*)d_in[3];
  const float* be1 = (const float*)d_in[4];
  const float* w2  = (const float*)d_in[5];
  const float* b2  = (const float*)d_in[6];
  const float* g2  = (const float*)d_in[7];
  const float* be2 = (const float*)d_in[8];
  const float* w3  = (const float*)d_in[9];
  const float* b3  = (const float*)d_in[10];
  const float* g3  = (const float*)d_in[11];
  const float* be3 = (const float*)d_in[12];
  const int N = in_sizes[0] / 6;  // (B=2, 3, N)
  float* out = (float*)d_out;

  char* wsb = (char*)d_ws;
  size_t off = 0;
  auto alloc = [&](size_t bytes)->char*{
    off = (off + 255) & ~(size_t)255;
    char* p = wsb + off; off += bytes; return p;
  };
  float* g0   = (float*)alloc((size_t)B_*DHW_*4);   // 4 MB
  float* wr1  = (float*)alloc(864*4);               // [27k][32o] fp32
  float* wr2  = (float*)alloc(55296*4);             // fp32 (fallback fused12)
  bf16*  wr2b = (bf16*) alloc(55296*2);             // [tap][64o][32i] bf16
  bf16*  wr3b = (bf16*) alloc(110592*2);            // [tap][64o][64i] bf16
  float* mins = (float*)alloc(8*4);
  float* stb  = (float*)alloc((size_t)3*NBUCK*128*4); // bucketed stats, 192 KB
  float* ss   = (float*)alloc(3*128*4);

  constexpr int DCHUNK = 16;
  constexpr int NSLAB  = D_ / DCHUNK;               // 8
  const size_t SX1  = (size_t)B_*DHW_*32*2;         // 64 MiB channel-last bf16
  const size_t SX2  = (size_t)B_*DHW_*64*2;         // 128 MiB channel-last bf16
  const size_t SMM  = (size_t)NSLAB*OUTN_*2;        // 8 MiB per min/max array

  // regionR: x1 (64MiB) aliases minp/maxp (16MiB) — disjoint lifetimes
  const size_t prefixEnd = (off + 255) & ~(size_t)255;
  const bool useMfma2 = ws_size >= prefixEnd + SX1 + SX2 + 1024;

  char* regionR = alloc(useMfma2 ? SX1 : 2*SMM);
  bf16* maxp = (bf16*)regionR;
  bf16* minp = (bf16*)(regionR + SMM);
  bf16* x1   = (bf16*)regionR;
  bf16* x2   = (bf16*)alloc(SX2);

  float* st1 = stb;
  float* st2 = stb + (size_t)NBUCK*128;
  float* st3 = stb + (size_t)2*NBUCK*128;

  // prologue
  zero_kernel<<<(B_*DHW_ + 255)/256, 256, 0, stream>>>(g0, B_*DHW_);
  zero_kernel<<<(3*NBUCK*128 + 255)/256, 256, 0, stream>>>(stb, 3*NBUCK*128);
  min_kernel<<<B_*3, 256, 0, stream>>>(pc, mins, N);
  scatter_kernel<<<(B_*N + 255)/256, 256, 0, stream>>>(pc, mins, g0, N);
  reorder_kernel<<<(864 + 255)/256, 256, 0, stream>>>(w1, wr1, 1, 32);
  reorder_kernel<<<(55296 + 255)/256, 256, 0, stream>>>(w2, wr2, 32, 64);
  reorder2b_kernel<<<(55296 + 255)/256, 256, 0, stream>>>(w2, wr2b);
  reorder3b_kernel<<<(110592 + 255)/256, 256, 0, stream>>>(w3, wr3b);

  dim3 cgrid(16, 128, 2);                           // (8h-tiles, d, b)
  dim3 mgrid(32, NSLAB, 2);                         // (4h-tiles, 16d-slabs, b)

  if (useMfma2){
    // conv1 once: raw x1 + BN1 stats; BN1+ReLU in-place; then MFMA conv2
    conv1act_kernel<<<cgrid, 256, 0, stream>>>(g0, wr1, b1, x1, st1);
    finalize_kernel<<<1, 64, 0, stream>>>(st1, g1, be1, ss, 32);
    bnact_kernel<32><<<(int)(((size_t)B_*DHW_*4 + 255)/256), 256, 0, stream>>>(x1, ss);
    conv2mfma_kernel<DCHUNK><<<mgrid, 256, 0, stream>>>(x1, wr2b, b2, x2, st2);
  } else {
    convstats_kernel<<<cgrid, 256, 0, stream>>>(g0, wr1, b1, st1);
    finalize_kernel<<<1, 64, 0, stream>>>(st1, g1, be1, ss, 32);
    fused12_kernel<<<cgrid, 256, 0, stream>>>(g0, wr1, b1, ss, wr2, b2, x2, st2);
  }
  finalize_kernel<<<1, 64, 0, stream>>>(st2, g2, be2, ss + 128, 64);

  bnact_kernel<64><<<(int)(((size_t)B_*DHW_*8 + 255)/256), 256, 0, stream>>>(x2, ss + 128);

  conv3mfma_kernel<DCHUNK><<<mgrid, 256, 0, stream>>>(x2, wr3b, b3, st3, minp, maxp);
  finalize_kernel<<<1, 64, 0, stream>>>(st3, g3, be3, ss + 256, 64);
  bevreduce_kernel<<<(OUTN_ + 255)/256, 256, 0, stream>>>(minp, maxp, ss + 256, out, NSLAB);
}